// Round 6
// baseline (165.288 us; speedup 1.0000x reference)
//
#include <hip/hip_runtime.h>
#include <hip/hip_bf16.h>

#define N_NODES 50000
#define KNN     16
#define NEDGE   (N_NODES*KNN)     // 800000
#define NTILE   (NEDGE/64)        // 12500 block-tiles of 64 edges (4 nodes)
#define NBLK    1024
#define SLOPE   0.01f
#define EPS     1e-5f

typedef __attribute__((ext_vector_type(8))) short bf16x8;
typedef __attribute__((ext_vector_type(4))) float f32x4;

__device__ __forceinline__ unsigned short f2bf(float f){
  union{__hip_bfloat16 h; unsigned short u;}v; v.h=__float2bfloat16(f); return v.u;
}
__device__ __forceinline__ bf16x8 asfrag(uint4 u){ union{uint4 v; bf16x8 b;}q; q.v=u; return q.b; }
__device__ __forceinline__ f32x4 MFMA(bf16x8 a, bf16x8 b, f32x4 c){
  return __builtin_amdgcn_mfma_f32_16x16x32_bf16(a, b, c, 0, 0, 0);
}
__device__ __forceinline__ float lrelu(float v){ return v>=0.f ? v : SLOPE*v; }

// ---- kInit: blocks 0..7 pack W frags (W1 concat-folded); 8..263 cvt x ------
// W-frag entry idx -> lane l=idx&63, frag fi: B[k=ks*32+(l>>4)*8+e][col=nf*16+(l&15)]
__global__ __launch_bounds__(256) void kInit(const float* __restrict__ W1,
    const float* __restrict__ W2, const float* __restrict__ W3,
    const float* __restrict__ x,
    unsigned short* __restrict__ wf, unsigned short* __restrict__ xb)
{
  if (blockIdx.x < 8){
    const int idx = blockIdx.x*256 + threadIdx.x;   // 2048 entries
    const float* W; int fi; bool fold = false;
    if (idx < 1024)      { W = W1; fi = idx >> 6; fold = (idx < 512); }
    else if (idx < 1536) { W = W2; fi = (idx-1024) >> 6; }
    else                 { W = W3; fi = (idx-1536) >> 6; }
    const int l  = idx & 63;
    const int ks = fi >> 2, nf = fi & 3;
    const int k0 = ks*32 + ((l>>4)<<3);
    const int col = nf*16 + (l&15);
    unsigned short* o = wf + (size_t)idx*8;
#pragma unroll
    for (int e=0;e<8;++e){
      float v = W[(size_t)(k0+e)*64 + col];
      if (fold) v -= W[(size_t)(k0+e+64)*64 + col];
      o[e] = f2bf(v);
    }
  } else {
    const int tid = (blockIdx.x-8)*256 + threadIdx.x;   // 65536 threads
    for (int i = tid; i < (N_NODES*64)/4; i += 65536){
      const float4 v = ((const float4*)x)[i];
      ushort4 o;
      o.x = f2bf(v.x); o.y = f2bf(v.y); o.z = f2bf(v.z); o.w = f2bf(v.w);
      ((ushort4*)xb)[i] = o;
    }
  }
}

// gather 4 A-fragments for one node's 16 edges (lane: lr=edge, lg=k-block)
#define GATHER(a0,a1,a2,a3)                                            \
  const unsigned short* xiP = xb + (size_t)node*64 + lg*8;             \
  const unsigned short* xjP = xb + (size_t)src*64  + lg*8;             \
  const bf16x8 a0 = *(const bf16x8*)(xiP);                             \
  const bf16x8 a1 = *(const bf16x8*)(xiP + 32);                        \
  const bf16x8 a2 = *(const bf16x8*)(xjP);                             \
  const bf16x8 a3 = *(const bf16x8*)(xjP + 32);

// ---- k1: gather + GEMM1 + stats1 (no store) --------------------------------
__global__ __launch_bounds__(256) void k1(const unsigned short* __restrict__ xb,
    const int* __restrict__ ei, const uint4* __restrict__ wf,
    float* __restrict__ part)
{
  __shared__ float red[4][128];
  const int t = threadIdx.x, w = t>>6, l = t&63;
  const int lr = l&15, lg = l>>4;

  bf16x8 wf1[16];
#pragma unroll
  for (int f=0;f<16;++f) wf1[f] = asfrag(wf[f*64 + l]);

  float sumP[4] = {0,0,0,0}, sqP[4] = {0,0,0,0};

  for (int tile = blockIdx.x; tile < NTILE; tile += gridDim.x){
    const int e0   = tile*64 + w*16;
    const int node = e0 >> 4;
    const int src  = ei[e0 + lr];
    GATHER(a0,a1,a2,a3)

    f32x4 acc[4];
#pragma unroll
    for (int nf=0;nf<4;++nf){
      acc[nf] = (f32x4){0.f,0.f,0.f,0.f};
      acc[nf] = MFMA(a0, wf1[0*4+nf], acc[nf]);
      acc[nf] = MFMA(a1, wf1[1*4+nf], acc[nf]);
      acc[nf] = MFMA(a2, wf1[2*4+nf], acc[nf]);
      acc[nf] = MFMA(a3, wf1[3*4+nf], acc[nf]);
    }
#pragma unroll
    for (int nf=0;nf<4;++nf){
#pragma unroll
      for (int r=0;r<4;++r){
        const float v = acc[nf][r];
        sumP[nf] += v; sqP[nf] = fmaf(v,v,sqP[nf]);
      }
    }
  }

#pragma unroll
  for (int nf=0;nf<4;++nf){
    float s = sumP[nf], q = sqP[nf];
    s += __shfl_xor(s,16,64); s += __shfl_xor(s,32,64);
    q += __shfl_xor(q,16,64); q += __shfl_xor(q,32,64);
    if (l < 16){ red[w][nf*16+l] = s; red[w][64+nf*16+l] = q; }
  }
  __syncthreads();
  if (t < 128)
    part[(size_t)t*NBLK + blockIdx.x] = red[0][t]+red[1][t]+red[2][t]+red[3][t];
}

// ---- kFin: 64 blocks, block c reduces sum-row c / sq-row 64+c --------------
__global__ __launch_bounds__(256) void kFin(const float* __restrict__ part,
    const float* __restrict__ g, const float* __restrict__ be,
    float* __restrict__ coefs)
{
  __shared__ float rs[256], rq[256];
  const int c = blockIdx.x, t = threadIdx.x;
  const float* ps = part + (size_t)c*NBLK;
  const float* pq = part + (size_t)(64+c)*NBLK;
  float s = 0.f, q = 0.f;
#pragma unroll
  for (int i=0;i<NBLK/256;++i){ s += ps[t + i*256]; q += pq[t + i*256]; }
  rs[t]=s; rq[t]=q;
  __syncthreads();
#pragma unroll
  for (int off=128; off>0; off>>=1){
    if (t < off){ rs[t]+=rs[t+off]; rq[t]+=rq[t+off]; }
    __syncthreads();
  }
  if (t==0){
    const float inv  = 1.0f/(float)NEDGE;
    const float mean = rs[0]*inv;
    const float var  = rq[0]*inv - mean*mean;
    const float a    = g[c]*rsqrtf(var + EPS);
    coefs[c]      = a;
    coefs[64 + c] = be[c] - mean*a;
  }
}

// BN+lrelu acc (ch=16nf+lr layout) -> bf16 into transpose buffer
#define BN_TO_BUF(ACC, AV, CV)                                          \
  _Pragma("unroll")                                                     \
  for (int nf=0;nf<4;++nf){                                             \
    _Pragma("unroll")                                                   \
    for (int r=0;r<4;++r){                                              \
      const float h = lrelu(fmaf(AV[nf], ACC[nf][r], CV[nf]));          \
      buf[w][4*lg+r][16*nf+lr] = f2bf(h);                               \
    }                                                                   \
  }

// read transposed A-frags (edge lr, k-chs 8lg.. / 32+8lg..)
#define BUF_TO_FRAGS(B0, B1)                                            \
  const bf16x8 B0 = *(const bf16x8*)&buf[w][lr][8*lg];                  \
  const bf16x8 B1 = *(const bf16x8*)&buf[w][lr][32+8*lg];

// ---- k2: gather + GEMM1 + BN1 + GEMM2 + stats2 -----------------------------
__global__ __launch_bounds__(256) void k2(const unsigned short* __restrict__ xb,
    const int* __restrict__ ei, const uint4* __restrict__ wf,
    const float* __restrict__ coefs, float* __restrict__ part)
{
  __shared__ __align__(16) unsigned short buf[4][16][72];
  __shared__ float red[4][128];
  const int t = threadIdx.x, w = t>>6, l = t&63;
  const int lr = l&15, lg = l>>4;

  bf16x8 wf1[16], wf2[8];
#pragma unroll
  for (int f=0;f<16;++f) wf1[f] = asfrag(wf[f*64 + l]);
#pragma unroll
  for (int f=0;f<8;++f)  wf2[f] = asfrag(wf[1024 + f*64 + l]);
  float a1v[4], c1v[4];
#pragma unroll
  for (int nf=0;nf<4;++nf){ a1v[nf]=coefs[nf*16+lr]; c1v[nf]=coefs[64+nf*16+lr]; }

  float sumP[4] = {0,0,0,0}, sqP[4] = {0,0,0,0};

  for (int tile = blockIdx.x; tile < NTILE; tile += gridDim.x){
    const int e0   = tile*64 + w*16;
    const int node = e0 >> 4;
    const int src  = ei[e0 + lr];
    GATHER(a0,a1,a2,a3)

    f32x4 acc[4];
#pragma unroll
    for (int nf=0;nf<4;++nf){
      acc[nf] = (f32x4){0.f,0.f,0.f,0.f};
      acc[nf] = MFMA(a0, wf1[0*4+nf], acc[nf]);
      acc[nf] = MFMA(a1, wf1[1*4+nf], acc[nf]);
      acc[nf] = MFMA(a2, wf1[2*4+nf], acc[nf]);
      acc[nf] = MFMA(a3, wf1[3*4+nf], acc[nf]);
    }
    BN_TO_BUF(acc, a1v, c1v)
    __syncthreads();
    BUF_TO_FRAGS(h0, h1)

    f32x4 acc2[4];
#pragma unroll
    for (int nf=0;nf<4;++nf){
      acc2[nf] = (f32x4){0.f,0.f,0.f,0.f};
      acc2[nf] = MFMA(h0, wf2[nf],   acc2[nf]);
      acc2[nf] = MFMA(h1, wf2[4+nf], acc2[nf]);
    }
#pragma unroll
    for (int nf=0;nf<4;++nf){
#pragma unroll
      for (int r=0;r<4;++r){
        const float v = acc2[nf][r];
        sumP[nf] += v; sqP[nf] = fmaf(v,v,sqP[nf]);
      }
    }
    __syncthreads();   // WAR: next iter rewrites buf
  }

#pragma unroll
  for (int nf=0;nf<4;++nf){
    float s = sumP[nf], q = sqP[nf];
    s += __shfl_xor(s,16,64); s += __shfl_xor(s,32,64);
    q += __shfl_xor(q,16,64); q += __shfl_xor(q,32,64);
    if (l < 16){ red[w][nf*16+l] = s; red[w][64+nf*16+l] = q; }
  }
  __syncthreads();
  if (t < 128)
    part[(size_t)t*NBLK + blockIdx.x] = red[0][t]+red[1][t]+red[2][t]+red[3][t];
}

// ---- k3: gather + GEMM1 + BN1 + GEMM2 + BN2 + GEMM3 + segmax + out ---------
__global__ __launch_bounds__(256) void k3(const unsigned short* __restrict__ xb,
    const int* __restrict__ ei, const uint4* __restrict__ wf,
    const float* __restrict__ coefs1, const float* __restrict__ coefs2,
    const float* __restrict__ b3, const float* __restrict__ x,
    float* __restrict__ out)
{
  __shared__ __align__(16) unsigned short buf[4][16][72];
  const int t = threadIdx.x, w = t>>6, l = t&63;
  const int lr = l&15, lg = l>>4;

  bf16x8 wf1[16], wf2[8], wf3[8];
#pragma unroll
  for (int f=0;f<16;++f) wf1[f] = asfrag(wf[f*64 + l]);
#pragma unroll
  for (int f=0;f<8;++f)  wf2[f] = asfrag(wf[1024 + f*64 + l]);
#pragma unroll
  for (int f=0;f<8;++f)  wf3[f] = asfrag(wf[1536 + f*64 + l]);
  float a1v[4], c1v[4], a2v[4], c2v[4], bb[4];
#pragma unroll
  for (int nf=0;nf<4;++nf){
    a1v[nf]=coefs1[nf*16+lr]; c1v[nf]=coefs1[64+nf*16+lr];
    a2v[nf]=coefs2[nf*16+lr]; c2v[nf]=coefs2[64+nf*16+lr];
    bb[nf] = b3[nf*16+lr];
  }

  for (int tile = blockIdx.x; tile < NTILE; tile += gridDim.x){
    const int e0   = tile*64 + w*16;
    const int node = e0 >> 4;
    const int src  = ei[e0 + lr];
    GATHER(a0,a1,a2,a3)

    f32x4 acc[4];
#pragma unroll
    for (int nf=0;nf<4;++nf){
      acc[nf] = (f32x4){0.f,0.f,0.f,0.f};
      acc[nf] = MFMA(a0, wf1[0*4+nf], acc[nf]);
      acc[nf] = MFMA(a1, wf1[1*4+nf], acc[nf]);
      acc[nf] = MFMA(a2, wf1[2*4+nf], acc[nf]);
      acc[nf] = MFMA(a3, wf1[3*4+nf], acc[nf]);
    }
    BN_TO_BUF(acc, a1v, c1v)
    __syncthreads();
    BUF_TO_FRAGS(h0, h1)

    f32x4 acc2[4];
#pragma unroll
    for (int nf=0;nf<4;++nf){
      acc2[nf] = (f32x4){0.f,0.f,0.f,0.f};
      acc2[nf] = MFMA(h0, wf2[nf],   acc2[nf]);
      acc2[nf] = MFMA(h1, wf2[4+nf], acc2[nf]);
    }
    __syncthreads();   // WAR before rewriting buf
    BN_TO_BUF(acc2, a2v, c2v)
    __syncthreads();
    BUF_TO_FRAGS(g0, g1)

    f32x4 acc3[4];
#pragma unroll
    for (int nf=0;nf<4;++nf){
      acc3[nf] = (f32x4){bb[nf],bb[nf],bb[nf],bb[nf]};
      acc3[nf] = MFMA(g0, wf3[nf],   acc3[nf]);
      acc3[nf] = MFMA(g1, wf3[4+nf], acc3[nf]);
    }

    // segment-max over the node's 16 edges, residual, lrelu, store
#pragma unroll
    for (int nf=0;nf<4;++nf){
      float m = fmaxf(fmaxf(acc3[nf][0],acc3[nf][1]), fmaxf(acc3[nf][2],acc3[nf][3]));
      m = fmaxf(m, __shfl_xor(m,16,64));
      m = fmaxf(m, __shfl_xor(m,32,64));
      if (l < 16){
        const float xv = x[(size_t)node*64 + nf*16 + l];
        const float o = m + xv;
        out[(size_t)node*64 + nf*16 + l] = lrelu(o);
      }
    }
    __syncthreads();   // WAR before next iter
  }
}

extern "C" void kernel_launch(void* const* d_in, const int* in_sizes, int n_in,
                              void* d_out, int out_size, void* d_ws, size_t ws_size,
                              hipStream_t stream) {
  const float* x   = (const float*)d_in[0];
  const int*   ei  = (const int*)d_in[1];
  const float* W1  = (const float*)d_in[2];
  const float* g1  = (const float*)d_in[4];
  const float* be1 = (const float*)d_in[5];
  const float* W2  = (const float*)d_in[6];
  const float* g2  = (const float*)d_in[8];
  const float* be2 = (const float*)d_in[9];
  const float* W3  = (const float*)d_in[10];
  const float* b3  = (const float*)d_in[11];
  float* out = (float*)d_out;

  // ws: coefs 1KB | part1 512KB | part2 512KB | wfb 32KB | xb 6.4MB  (~7.5MB)
  float*          coefs = (float*)d_ws;
  float*          part1 = (float*)((char*)d_ws + 1024);
  float*          part2 = part1 + (size_t)NBLK*128;
  unsigned short* wfb   = (unsigned short*)((char*)part2 + (size_t)NBLK*128*4);
  unsigned short* xb    = (unsigned short*)((char*)wfb + 32768);

  kInit<<<264, 256, 0, stream>>>(W1, W2, W3, x, wfb, xb);
  k1<<<NBLK, 256, 0, stream>>>(xb, ei, (const uint4*)wfb, part1);
  kFin<<<64, 256, 0, stream>>>(part1, g1, be1, coefs);
  k2<<<NBLK, 256, 0, stream>>>(xb, ei, (const uint4*)wfb, coefs, part2);
  kFin<<<64, 256, 0, stream>>>(part2, g2, be2, coefs + 128);
  k3<<<NBLK, 256, 0, stream>>>(xb, ei, (const uint4*)wfb, coefs, coefs + 128,
                               b3, x, out);
}

// Round 7
// 146.842 us; speedup vs baseline: 1.1256x; 1.1256x over previous
//
#include <hip/hip_runtime.h>
#include <hip/hip_bf16.h>

#define N_NODES 50000
#define KNN     16
#define NEDGE   (N_NODES*KNN)     // 800000
#define NTILE   (NEDGE/64)        // 12500 tiles of 64 edges (4 nodes)
#define NWT     (N_NODES/16)      // 3125 wave-tiles for kUV
#define NBLK    1024
#define SLOPE   0.01f
#define EPS     1e-5f

typedef __attribute__((ext_vector_type(8))) short bf16x8;
typedef __attribute__((ext_vector_type(4))) float f32x4;

__device__ __forceinline__ float bfbits(unsigned u){ union{unsigned u;float f;}v; v.u=u; return v.f; }
__device__ __forceinline__ unsigned short f2bf(float f){
  union{__hip_bfloat16 h; unsigned short u;}v; v.h=__float2bfloat16(f); return v.u;
}
__device__ __forceinline__ bf16x8 asfrag(uint4 u){ union{uint4 v; bf16x8 b;}q; q.v=u; return q.b; }
__device__ __forceinline__ f32x4 MFMA(bf16x8 a, bf16x8 b, f32x4 c){
  return __builtin_amdgcn_mfma_f32_16x16x32_bf16(a, b, c, 0, 0, 0);
}
__device__ __forceinline__ float lrelu(float v){ return v>=0.f ? v : SLOPE*v; }

__device__ __forceinline__ void unp8(bf16x8 v, float* o){
  union{bf16x8 b; unsigned u[4];}q; q.b=v;
#pragma unroll
  for (int w=0;w<4;++w){
    o[2*w]   = bfbits(q.u[w]<<16);
    o[2*w+1] = bfbits(q.u[w]&0xffff0000u);
  }
}
__device__ __forceinline__ bf16x8 pack8f(const float* f){
  bf16x8 r;
#pragma unroll
  for (int e=0;e<8;++e) r[e] = (short)f2bf(f[e]);
  return r;
}
__device__ __forceinline__ bf16x8 pack8(float4 a, float4 b){
  bf16x8 r;
  r[0]=(short)f2bf(a.x); r[1]=(short)f2bf(a.y); r[2]=(short)f2bf(a.z); r[3]=(short)f2bf(a.w);
  r[4]=(short)f2bf(b.x); r[5]=(short)f2bf(b.y); r[6]=(short)f2bf(b.z); r[7]=(short)f2bf(b.w);
  return r;
}

// ---- kInit: pack W frags. W1 folded: frags 0..7 = A-B (k 0..63), 8..15 = B -
__global__ __launch_bounds__(256) void kInit(const float* __restrict__ W1,
    const float* __restrict__ W2, const float* __restrict__ W3,
    unsigned short* __restrict__ wf)
{
  const int idx = blockIdx.x*256 + threadIdx.x;   // 2048 entries
  const float* W; int fi; bool fold = false;
  if (idx < 1024)      { W = W1; fi = idx >> 6; fold = (idx < 512); }
  else if (idx < 1536) { W = W2; fi = (idx-1024) >> 6; }
  else                 { W = W3; fi = (idx-1536) >> 6; }
  const int l  = idx & 63;
  const int ks = fi >> 2, nf = fi & 3;
  const int k0 = ks*32 + ((l>>4)<<3);
  const int col = nf*16 + (l&15);
  unsigned short* o = wf + (size_t)idx*8;
#pragma unroll
  for (int e=0;e<8;++e){
    float v = W[(size_t)(k0+e)*64 + col];
    if (fold) v -= W[(size_t)(k0+e+64)*64 + col];
    o[e] = f2bf(v);
  }
}

// ---- kUV: per-node U = x(A-B), V = xB (bf16) -------------------------------
__global__ __launch_bounds__(256) void kUV(const float* __restrict__ x,
    const uint4* __restrict__ wf, unsigned short* __restrict__ Ub,
    unsigned short* __restrict__ Vb)
{
  const int t = threadIdx.x, w = t>>6, l = t&63, lr = l&15, lg = l>>4;
  const int wt = blockIdx.x*4 + w;
  if (wt >= NWT) return;
  bf16x8 wfr[16];
#pragma unroll
  for (int f=0;f<16;++f) wfr[f] = asfrag(wf[f*64 + l]);
  const int n0 = wt*16;
  const float* xr = x + (size_t)(n0+lr)*64 + lg*8;
  const bf16x8 a0 = pack8(((const float4*)xr)[0],      ((const float4*)xr)[1]);
  const bf16x8 a1 = pack8(((const float4*)(xr+32))[0], ((const float4*)(xr+32))[1]);

  f32x4 aU[4], aV[4];
#pragma unroll
  for (int nf=0;nf<4;++nf){
    aU[nf] = (f32x4){0,0,0,0};
    aU[nf] = MFMA(a0, wfr[nf],    aU[nf]);
    aU[nf] = MFMA(a1, wfr[4+nf],  aU[nf]);
    aV[nf] = (f32x4){0,0,0,0};
    aV[nf] = MFMA(a0, wfr[8+nf],  aV[nf]);
    aV[nf] = MFMA(a1, wfr[12+nf], aV[nf]);
  }
#pragma unroll
  for (int nf=0;nf<4;++nf)
#pragma unroll
    for (int r=0;r<4;++r){
      const size_t o = (size_t)(n0 + 4*lg + r)*64 + 16*nf + lr;
      Ub[o] = f2bf(aU[nf][r]);
      Vb[o] = f2bf(aV[nf][r]);
    }
}

// ---- kS1: stats of z1 = U[dst] + V[src] (no MFMA) --------------------------
__global__ __launch_bounds__(256) void kS1(const unsigned short* __restrict__ Ub,
    const unsigned short* __restrict__ Vb, const int* __restrict__ ei,
    float* __restrict__ part)
{
  __shared__ float red[4][128];
  const int t = threadIdx.x, w = t>>6, l = t&63, lr = l&15, lg = l>>4;

  float s[16], q[16];
#pragma unroll
  for (int k=0;k<16;++k){ s[k]=0.f; q[k]=0.f; }

  int srcn = ei[blockIdx.x*64 + w*16 + lr];
  for (int tile = blockIdx.x; tile < NTILE; tile += gridDim.x){
    const int e0 = tile*64 + w*16, node = e0>>4;
    const int src = srcn;
    const int nt = tile + gridDim.x;
    if (nt < NTILE) srcn = ei[nt*64 + w*16 + lr];

    const unsigned short* Ur = Ub + (size_t)node*64 + lg*8;
    const unsigned short* Vr = Vb + (size_t)src*64  + lg*8;
    const bf16x8 u0 = *(const bf16x8*)Ur,      u1 = *(const bf16x8*)(Ur+32);
    const bf16x8 v0 = *(const bf16x8*)Vr,      v1 = *(const bf16x8*)(Vr+32);
    float fu[8], fv[8];
    unp8(u0,fu); unp8(v0,fv);
#pragma unroll
    for (int e=0;e<8;++e){ const float z = fu[e]+fv[e]; s[e]+=z; q[e]=fmaf(z,z,q[e]); }
    unp8(u1,fu); unp8(v1,fv);
#pragma unroll
    for (int e=0;e<8;++e){ const float z = fu[e]+fv[e]; s[8+e]+=z; q[8+e]=fmaf(z,z,q[8+e]); }
  }

#pragma unroll
  for (int k=0;k<16;++k){
    float a=s[k]; a+=__shfl_xor(a,1,64); a+=__shfl_xor(a,2,64);
    a+=__shfl_xor(a,4,64); a+=__shfl_xor(a,8,64); s[k]=a;
    float b=q[k]; b+=__shfl_xor(b,1,64); b+=__shfl_xor(b,2,64);
    b+=__shfl_xor(b,4,64); b+=__shfl_xor(b,8,64); q[k]=b;
  }
  if (lr == 0){
#pragma unroll
    for (int e=0;e<8;++e){
      red[w][8*lg+e]       = s[e];
      red[w][32+8*lg+e]    = s[8+e];
      red[w][64+8*lg+e]    = q[e];
      red[w][96+8*lg+e]    = q[8+e];
    }
  }
  __syncthreads();
  if (t < 128)
    part[(size_t)t*NBLK + blockIdx.x] = red[0][t]+red[1][t]+red[2][t]+red[3][t];
}

// ---- kFin ------------------------------------------------------------------
__global__ __launch_bounds__(256) void kFin(const float* __restrict__ part,
    const float* __restrict__ g, const float* __restrict__ be,
    float* __restrict__ coefs)
{
  __shared__ float rs[256], rq[256];
  const int c = blockIdx.x, t = threadIdx.x;
  const float* ps = part + (size_t)c*NBLK;
  const float* pq = part + (size_t)(64+c)*NBLK;
  float s = 0.f, q = 0.f;
#pragma unroll
  for (int i=0;i<NBLK/256;++i){ s += ps[t + i*256]; q += pq[t + i*256]; }
  rs[t]=s; rq[t]=q;
  __syncthreads();
#pragma unroll
  for (int off=128; off>0; off>>=1){
    if (t < off){ rs[t]+=rs[t+off]; rq[t]+=rq[t+off]; }
    __syncthreads();
  }
  if (t==0){
    const float inv  = 1.0f/(float)NEDGE;
    const float mean = rs[0]*inv;
    const float var  = rq[0]*inv - mean*mean;
    const float a    = g[c]*rsqrtf(var + EPS);
    coefs[c]      = a;
    coefs[64 + c] = be[c] - mean*a;
  }
}

// ---- kScale: U' = a*U + c ; V' = a*V (in place, fold BN1) ------------------
__global__ __launch_bounds__(256) void kScale(unsigned short* __restrict__ Ub,
    unsigned short* __restrict__ Vb, const float* __restrict__ coefs)
{
  const int j = blockIdx.x*256 + threadIdx.x;     // 400000 jobs of 8 ch
  if (j >= N_NODES*8) return;
  const int c0 = (j & 7)*8;
  float a[8], c[8], f[8];
#pragma unroll
  for (int e=0;e<8;++e){ a[e]=coefs[c0+e]; c[e]=coefs[64+c0+e]; }
  bf16x8 u = ((const bf16x8*)Ub)[j];
  unp8(u,f);
#pragma unroll
  for (int e=0;e<8;++e) f[e] = fmaf(a[e], f[e], c[e]);
  ((bf16x8*)Ub)[j] = pack8f(f);
  bf16x8 v = ((const bf16x8*)Vb)[j];
  unp8(v,f);
#pragma unroll
  for (int e=0;e<8;++e) f[e] *= a[e];
  ((bf16x8*)Vb)[j] = pack8f(f);
}

// build h1 fragments from U',V'
#define H1FRAGS(h0f, h1f)                                               \
  const unsigned short* Ur = Ub + (size_t)node*64 + lg*8;               \
  const unsigned short* Vr = Vb + (size_t)src*64  + lg*8;               \
  bf16x8 h0f, h1f;                                                      \
  {                                                                     \
    const bf16x8 u0 = *(const bf16x8*)Ur, u1 = *(const bf16x8*)(Ur+32); \
    const bf16x8 v0 = *(const bf16x8*)Vr, v1 = *(const bf16x8*)(Vr+32); \
    float fu[8], fv[8], h[8];                                           \
    unp8(u0,fu); unp8(v0,fv);                                           \
    _Pragma("unroll")                                                   \
    for (int e=0;e<8;++e) h[e] = lrelu(fu[e]+fv[e]);                    \
    h0f = pack8f(h);                                                    \
    unp8(u1,fu); unp8(v1,fv);                                           \
    _Pragma("unroll")                                                   \
    for (int e=0;e<8;++e) h[e] = lrelu(fu[e]+fv[e]);                    \
    h1f = pack8f(h);                                                    \
  }

// ---- kS2: h1 = lrelu(U'+V'); z2 = h1@W2; stats2 ----------------------------
__global__ __launch_bounds__(256) void kS2(const unsigned short* __restrict__ Ub,
    const unsigned short* __restrict__ Vb, const int* __restrict__ ei,
    const uint4* __restrict__ wf, float* __restrict__ part)
{
  __shared__ float red[4][128];
  const int t = threadIdx.x, w = t>>6, l = t&63, lr = l&15, lg = l>>4;

  bf16x8 wf2[8];
#pragma unroll
  for (int f=0;f<8;++f) wf2[f] = asfrag(wf[1024 + f*64 + l]);

  float sumP[4] = {0,0,0,0}, sqP[4] = {0,0,0,0};

  int srcn = ei[blockIdx.x*64 + w*16 + lr];
  for (int tile = blockIdx.x; tile < NTILE; tile += gridDim.x){
    const int e0 = tile*64 + w*16, node = e0>>4;
    const int src = srcn;
    const int nt = tile + gridDim.x;
    if (nt < NTILE) srcn = ei[nt*64 + w*16 + lr];

    H1FRAGS(h0, h1)

    f32x4 acc[4];
#pragma unroll
    for (int nf=0;nf<4;++nf){
      acc[nf] = (f32x4){0,0,0,0};
      acc[nf] = MFMA(h0, wf2[nf],   acc[nf]);
      acc[nf] = MFMA(h1, wf2[4+nf], acc[nf]);
    }
#pragma unroll
    for (int nf=0;nf<4;++nf)
#pragma unroll
      for (int r=0;r<4;++r){
        const float v = acc[nf][r];
        sumP[nf] += v; sqP[nf] = fmaf(v,v,sqP[nf]);
      }
  }

#pragma unroll
  for (int nf=0;nf<4;++nf){
    float s = sumP[nf], q = sqP[nf];
    s += __shfl_xor(s,16,64); s += __shfl_xor(s,32,64);
    q += __shfl_xor(q,16,64); q += __shfl_xor(q,32,64);
    if (l < 16){ red[w][nf*16+l] = s; red[w][64+nf*16+l] = q; }
  }
  __syncthreads();
  if (t < 128)
    part[(size_t)t*NBLK + blockIdx.x] = red[0][t]+red[1][t]+red[2][t]+red[3][t];
}

// ---- kS3: h1 -> z2 -> BN2+lrelu -> z3 -> segmax -> residual -> out ---------
__global__ __launch_bounds__(256) void kS3(const unsigned short* __restrict__ Ub,
    const unsigned short* __restrict__ Vb, const int* __restrict__ ei,
    const uint4* __restrict__ wf, const float* __restrict__ coefs2,
    const float* __restrict__ b3, const float* __restrict__ x,
    float* __restrict__ out)
{
  __shared__ __align__(16) unsigned short buf[4][16][72];   // per-wave
  const int t = threadIdx.x, w = t>>6, l = t&63, lr = l&15, lg = l>>4;

  bf16x8 wf2[8], wf3[8];
#pragma unroll
  for (int f=0;f<8;++f) wf2[f] = asfrag(wf[1024 + f*64 + l]);
#pragma unroll
  for (int f=0;f<8;++f) wf3[f] = asfrag(wf[1536 + f*64 + l]);
  float a2v[4], c2v[4], bb[4];
#pragma unroll
  for (int nf=0;nf<4;++nf){
    a2v[nf]=coefs2[nf*16+lr]; c2v[nf]=coefs2[64+nf*16+lr];
    bb[nf] = b3[nf*16+lr];
  }

  int srcn = ei[blockIdx.x*64 + w*16 + lr];
  for (int tile = blockIdx.x; tile < NTILE; tile += gridDim.x){
    const int e0 = tile*64 + w*16, node = e0>>4;
    const int src = srcn;
    const int nt = tile + gridDim.x;
    if (nt < NTILE) srcn = ei[nt*64 + w*16 + lr];

    H1FRAGS(h0, h1)

    f32x4 acc2[4];
#pragma unroll
    for (int nf=0;nf<4;++nf){
      acc2[nf] = (f32x4){0,0,0,0};
      acc2[nf] = MFMA(h0, wf2[nf],   acc2[nf]);
      acc2[nf] = MFMA(h1, wf2[4+nf], acc2[nf]);
    }
    // BN2 + lrelu -> per-wave transpose buffer (D rows=edges 4lg+r, cols=16nf+lr)
#pragma unroll
    for (int nf=0;nf<4;++nf)
#pragma unroll
      for (int r=0;r<4;++r){
        const float h = lrelu(fmaf(a2v[nf], acc2[nf][r], c2v[nf]));
        buf[w][4*lg+r][16*nf+lr] = f2bf(h);
      }
    // read back as A-frags (same wave; compiler orders via lgkmcnt)
    const bf16x8 g0 = *(const bf16x8*)&buf[w][lr][8*lg];
    const bf16x8 g1 = *(const bf16x8*)&buf[w][lr][32+8*lg];

    f32x4 acc3[4];
#pragma unroll
    for (int nf=0;nf<4;++nf){
      acc3[nf] = (f32x4){bb[nf],bb[nf],bb[nf],bb[nf]};
      acc3[nf] = MFMA(g0, wf3[nf],   acc3[nf]);
      acc3[nf] = MFMA(g1, wf3[4+nf], acc3[nf]);
    }

#pragma unroll
    for (int nf=0;nf<4;++nf){
      float m = fmaxf(fmaxf(acc3[nf][0],acc3[nf][1]), fmaxf(acc3[nf][2],acc3[nf][3]));
      m = fmaxf(m, __shfl_xor(m,16,64));
      m = fmaxf(m, __shfl_xor(m,32,64));
      if (l < 16){
        const float xv = x[(size_t)node*64 + nf*16 + l];
        out[(size_t)node*64 + nf*16 + l] = lrelu(m + xv);
      }
    }
  }
}

extern "C" void kernel_launch(void* const* d_in, const int* in_sizes, int n_in,
                              void* d_out, int out_size, void* d_ws, size_t ws_size,
                              hipStream_t stream) {
  const float* x   = (const float*)d_in[0];
  const int*   ei  = (const int*)d_in[1];
  const float* W1  = (const float*)d_in[2];
  const float* g1  = (const float*)d_in[4];
  const float* be1 = (const float*)d_in[5];
  const float* W2  = (const float*)d_in[6];
  const float* g2  = (const float*)d_in[8];
  const float* be2 = (const float*)d_in[9];
  const float* W3  = (const float*)d_in[10];
  const float* b3  = (const float*)d_in[11];
  float* out = (float*)d_out;

  // ws: coefs 1KB | part1 512KB | part2 512KB | wfb 32KB | U 6.4MB | V 6.4MB
  float*          coefs = (float*)d_ws;
  float*          part1 = (float*)((char*)d_ws + 1024);
  float*          part2 = part1 + (size_t)NBLK*128;
  unsigned short* wfb   = (unsigned short*)((char*)part2 + (size_t)NBLK*128*4);
  unsigned short* Ub    = (unsigned short*)((char*)wfb + 32768);
  unsigned short* Vb    = Ub + (size_t)N_NODES*64;

  kInit<<<8, 256, 0, stream>>>(W1, W2, W3, wfb);
  kUV<<<(NWT+3)/4, 256, 0, stream>>>(x, (const uint4*)wfb, Ub, Vb);
  kS1<<<NBLK, 256, 0, stream>>>(Ub, Vb, ei, part1);
  kFin<<<64, 256, 0, stream>>>(part1, g1, be1, coefs);
  kScale<<<(N_NODES*8 + 255)/256, 256, 0, stream>>>(Ub, Vb, coefs);
  kS2<<<NBLK, 256, 0, stream>>>(Ub, Vb, ei, (const uint4*)wfb, part2);
  kFin<<<64, 256, 0, stream>>>(part2, g2, be2, coefs + 128);
  kS3<<<NBLK, 256, 0, stream>>>(Ub, Vb, ei, (const uint4*)wfb, coefs + 128,
                                b3, x, out);
}

// Round 8
// 135.915 us; speedup vs baseline: 1.2161x; 1.0804x over previous
//
#include <hip/hip_runtime.h>
#include <hip/hip_bf16.h>

#define N_NODES 50000
#define KNN     16
#define NEDGE   (N_NODES*KNN)     // 800000
#define NTILE   (NEDGE/64)        // 12500 tiles of 64 edges (4 nodes)
#define NWT     (N_NODES/16)      // 3125 wave-tiles for kUV
#define NBLK    2048
#define SLOPE   0.01f
#define EPS     1e-5f

typedef __attribute__((ext_vector_type(8))) short bf16x8;
typedef __attribute__((ext_vector_type(4))) float f32x4;

__device__ __forceinline__ float bfbits(unsigned u){ union{unsigned u;float f;}v; v.u=u; return v.f; }
__device__ __forceinline__ unsigned short f2bf(float f){
  union{__hip_bfloat16 h; unsigned short u;}v; v.h=__float2bfloat16(f); return v.u;
}
__device__ __forceinline__ bf16x8 asfrag(uint4 u){ union{uint4 v; bf16x8 b;}q; q.v=u; return q.b; }
__device__ __forceinline__ f32x4 MFMA(bf16x8 a, bf16x8 b, f32x4 c){
  return __builtin_amdgcn_mfma_f32_16x16x32_bf16(a, b, c, 0, 0, 0);
}
__device__ __forceinline__ float lrelu(float v){ return v>=0.f ? v : SLOPE*v; }

__device__ __forceinline__ void unp8(bf16x8 v, float* o){
  union{bf16x8 b; unsigned u[4];}q; q.b=v;
#pragma unroll
  for (int w=0;w<4;++w){
    o[2*w]   = bfbits(q.u[w]<<16);
    o[2*w+1] = bfbits(q.u[w]&0xffff0000u);
  }
}
__device__ __forceinline__ bf16x8 pack8f(const float* f){
  bf16x8 r;
#pragma unroll
  for (int e=0;e<8;++e) r[e] = (short)f2bf(f[e]);
  return r;
}
__device__ __forceinline__ bf16x8 pack8(float4 a, float4 b){
  bf16x8 r;
  r[0]=(short)f2bf(a.x); r[1]=(short)f2bf(a.y); r[2]=(short)f2bf(a.z); r[3]=(short)f2bf(a.w);
  r[4]=(short)f2bf(b.x); r[5]=(short)f2bf(b.y); r[6]=(short)f2bf(b.z); r[7]=(short)f2bf(b.w);
  return r;
}

// ---- kInit: pack W frags. W1 folded: frags 0..7 = A-B (k 0..63), 8..15 = B -
__global__ __launch_bounds__(256) void kInit(const float* __restrict__ W1,
    const float* __restrict__ W2, const float* __restrict__ W3,
    unsigned short* __restrict__ wf)
{
  const int idx = blockIdx.x*256 + threadIdx.x;   // 2048 entries
  const float* W; int fi; bool fold = false;
  if (idx < 1024)      { W = W1; fi = idx >> 6; fold = (idx < 512); }
  else if (idx < 1536) { W = W2; fi = (idx-1024) >> 6; }
  else                 { W = W3; fi = (idx-1536) >> 6; }
  const int l  = idx & 63;
  const int ks = fi >> 2, nf = fi & 3;
  const int k0 = ks*32 + ((l>>4)<<3);
  const int col = nf*16 + (l&15);
  unsigned short* o = wf + (size_t)idx*8;
#pragma unroll
  for (int e=0;e<8;++e){
    float v = W[(size_t)(k0+e)*64 + col];
    if (fold) v -= W[(size_t)(k0+e+64)*64 + col];
    o[e] = f2bf(v);
  }
}

// ---- kUV: per-node U = x(A-B), V = xB (bf16) -------------------------------
__global__ __launch_bounds__(256) void kUV(const float* __restrict__ x,
    const uint4* __restrict__ wf, unsigned short* __restrict__ Ub,
    unsigned short* __restrict__ Vb)
{
  const int t = threadIdx.x, w = t>>6, l = t&63, lr = l&15, lg = l>>4;
  const int wt = blockIdx.x*4 + w;
  if (wt >= NWT) return;
  bf16x8 wfr[16];
#pragma unroll
  for (int f=0;f<16;++f) wfr[f] = asfrag(wf[f*64 + l]);
  const int n0 = wt*16;
  const float* xr = x + (size_t)(n0+lr)*64 + lg*8;
  const bf16x8 a0 = pack8(((const float4*)xr)[0],      ((const float4*)xr)[1]);
  const bf16x8 a1 = pack8(((const float4*)(xr+32))[0], ((const float4*)(xr+32))[1]);

  f32x4 aU[4], aV[4];
#pragma unroll
  for (int nf=0;nf<4;++nf){
    aU[nf] = (f32x4){0,0,0,0};
    aU[nf] = MFMA(a0, wfr[nf],    aU[nf]);
    aU[nf] = MFMA(a1, wfr[4+nf],  aU[nf]);
    aV[nf] = (f32x4){0,0,0,0};
    aV[nf] = MFMA(a0, wfr[8+nf],  aV[nf]);
    aV[nf] = MFMA(a1, wfr[12+nf], aV[nf]);
  }
#pragma unroll
  for (int nf=0;nf<4;++nf)
#pragma unroll
    for (int r=0;r<4;++r){
      const size_t o = (size_t)(n0 + 4*lg + r)*64 + 16*nf + lr;
      Ub[o] = f2bf(aU[nf][r]);
      Vb[o] = f2bf(aV[nf][r]);
    }
}

// load U/V fragments for (nodeId, srcId)
#define LOADUV(U0,U1,V0,V1, nodeId, srcId)                               \
  {                                                                      \
    const unsigned short* Ur = Ub + (size_t)(nodeId)*64 + lg*8;          \
    const unsigned short* Vr = Vb + (size_t)(srcId)*64  + lg*8;          \
    U0 = *(const bf16x8*)Ur; U1 = *(const bf16x8*)(Ur+32);               \
    V0 = *(const bf16x8*)Vr; V1 = *(const bf16x8*)(Vr+32);               \
  }

// ---- kS1: stats of z1 = U[dst] + V[src] (no MFMA), pipelined ---------------
__global__ __launch_bounds__(256) void kS1(const unsigned short* __restrict__ Ub,
    const unsigned short* __restrict__ Vb, const int* __restrict__ ei,
    float* __restrict__ part)
{
  __shared__ float red[4][128];
  const int t = threadIdx.x, w = t>>6, l = t&63, lr = l&15, lg = l>>4;
  const int G = gridDim.x;

  float s[16], q[16];
#pragma unroll
  for (int k=0;k<16;++k){ s[k]=0.f; q[k]=0.f; }

  int tile = blockIdx.x;
  int srcB = (tile+G < NTILE) ? ei[(tile+G)*64 + w*16 + lr] : 0;
  bf16x8 cu0,cu1,cv0,cv1;
  {
    const int srcA = ei[tile*64 + w*16 + lr];
    LOADUV(cu0,cu1,cv0,cv1, tile*4+w, srcA)
  }
  for (; tile < NTILE; tile += G){
    const int nt = tile + G, nt2 = tile + 2*G;
    const int srcC = (nt2 < NTILE) ? ei[nt2*64 + w*16 + lr] : 0;
    bf16x8 nu0,nu1,nv0,nv1;
    const int nnode = (nt < NTILE) ? nt*4+w : 0;
    LOADUV(nu0,nu1,nv0,nv1, nnode, srcB)

    float fu[8], fv[8];
    unp8(cu0,fu); unp8(cv0,fv);
#pragma unroll
    for (int e=0;e<8;++e){ const float z = fu[e]+fv[e]; s[e]+=z; q[e]=fmaf(z,z,q[e]); }
    unp8(cu1,fu); unp8(cv1,fv);
#pragma unroll
    for (int e=0;e<8;++e){ const float z = fu[e]+fv[e]; s[8+e]+=z; q[8+e]=fmaf(z,z,q[8+e]); }

    cu0=nu0; cu1=nu1; cv0=nv0; cv1=nv1; srcB=srcC;
  }

#pragma unroll
  for (int k=0;k<16;++k){
    float a=s[k]; a+=__shfl_xor(a,1,64); a+=__shfl_xor(a,2,64);
    a+=__shfl_xor(a,4,64); a+=__shfl_xor(a,8,64); s[k]=a;
    float b=q[k]; b+=__shfl_xor(b,1,64); b+=__shfl_xor(b,2,64);
    b+=__shfl_xor(b,4,64); b+=__shfl_xor(b,8,64); q[k]=b;
  }
  if (lr == 0){
#pragma unroll
    for (int e=0;e<8;++e){
      red[w][8*lg+e]    = s[e];
      red[w][32+8*lg+e] = s[8+e];
      red[w][64+8*lg+e] = q[e];
      red[w][96+8*lg+e] = q[8+e];
    }
  }
  __syncthreads();
  if (t < 128)
    part[(size_t)t*NBLK + blockIdx.x] = red[0][t]+red[1][t]+red[2][t]+red[3][t];
}

// ---- kFin ------------------------------------------------------------------
__global__ __launch_bounds__(256) void kFin(const float* __restrict__ part,
    const float* __restrict__ g, const float* __restrict__ be,
    float* __restrict__ coefs)
{
  __shared__ float rs[256], rq[256];
  const int c = blockIdx.x, t = threadIdx.x;
  const float* ps = part + (size_t)c*NBLK;
  const float* pq = part + (size_t)(64+c)*NBLK;
  float s = 0.f, q = 0.f;
#pragma unroll
  for (int i=0;i<NBLK/256;++i){ s += ps[t + i*256]; q += pq[t + i*256]; }
  rs[t]=s; rq[t]=q;
  __syncthreads();
#pragma unroll
  for (int off=128; off>0; off>>=1){
    if (t < off){ rs[t]+=rs[t+off]; rq[t]+=rq[t+off]; }
    __syncthreads();
  }
  if (t==0){
    const float inv  = 1.0f/(float)NEDGE;
    const float mean = rs[0]*inv;
    const float var  = rq[0]*inv - mean*mean;
    const float a    = g[c]*rsqrtf(var + EPS);
    coefs[c]      = a;
    coefs[64 + c] = be[c] - mean*a;
  }
}

// ---- kScale: U' = a*U + c ; V' = a*V (in place, fold BN1) ------------------
__global__ __launch_bounds__(256) void kScale(unsigned short* __restrict__ Ub,
    unsigned short* __restrict__ Vb, const float* __restrict__ coefs)
{
  const int j = blockIdx.x*256 + threadIdx.x;     // 400000 jobs of 8 ch
  if (j >= N_NODES*8) return;
  const int c0 = (j & 7)*8;
  float a[8], c[8], f[8];
#pragma unroll
  for (int e=0;e<8;++e){ a[e]=coefs[c0+e]; c[e]=coefs[64+c0+e]; }
  bf16x8 u = ((const bf16x8*)Ub)[j];
  unp8(u,f);
#pragma unroll
  for (int e=0;e<8;++e) f[e] = fmaf(a[e], f[e], c[e]);
  ((bf16x8*)Ub)[j] = pack8f(f);
  bf16x8 v = ((const bf16x8*)Vb)[j];
  unp8(v,f);
#pragma unroll
  for (int e=0;e<8;++e) f[e] *= a[e];
  ((bf16x8*)Vb)[j] = pack8f(f);
}

// h1 fragments from already-loaded U',V' registers
#define H1COMP(h0f, h1f, U0,U1,V0,V1)                                   \
  bf16x8 h0f, h1f;                                                      \
  {                                                                     \
    float fu[8], fv[8], h[8];                                           \
    unp8(U0,fu); unp8(V0,fv);                                           \
    _Pragma("unroll")                                                   \
    for (int e=0;e<8;++e) h[e] = lrelu(fu[e]+fv[e]);                    \
    h0f = pack8f(h);                                                    \
    unp8(U1,fu); unp8(V1,fv);                                           \
    _Pragma("unroll")                                                   \
    for (int e=0;e<8;++e) h[e] = lrelu(fu[e]+fv[e]);                    \
    h1f = pack8f(h);                                                    \
  }

// ---- kS2: h1 = lrelu(U'+V'); z2 = h1@W2; stats2; pipelined -----------------
__global__ __launch_bounds__(256) void kS2(const unsigned short* __restrict__ Ub,
    const unsigned short* __restrict__ Vb, const int* __restrict__ ei,
    const uint4* __restrict__ wf, float* __restrict__ part)
{
  __shared__ float red[4][128];
  const int t = threadIdx.x, w = t>>6, l = t&63, lr = l&15, lg = l>>4;
  const int G = gridDim.x;

  bf16x8 wf2[8];
#pragma unroll
  for (int f=0;f<8;++f) wf2[f] = asfrag(wf[1024 + f*64 + l]);

  float sumP[4] = {0,0,0,0}, sqP[4] = {0,0,0,0};

  int tile = blockIdx.x;
  int srcB = (tile+G < NTILE) ? ei[(tile+G)*64 + w*16 + lr] : 0;
  bf16x8 cu0,cu1,cv0,cv1;
  {
    const int srcA = ei[tile*64 + w*16 + lr];
    LOADUV(cu0,cu1,cv0,cv1, tile*4+w, srcA)
  }
  for (; tile < NTILE; tile += G){
    const int nt = tile + G, nt2 = tile + 2*G;
    const int srcC = (nt2 < NTILE) ? ei[nt2*64 + w*16 + lr] : 0;
    bf16x8 nu0,nu1,nv0,nv1;
    const int nnode = (nt < NTILE) ? nt*4+w : 0;
    LOADUV(nu0,nu1,nv0,nv1, nnode, srcB)

    H1COMP(h0, h1, cu0,cu1,cv0,cv1)

    f32x4 acc[4];
#pragma unroll
    for (int nf=0;nf<4;++nf){
      acc[nf] = (f32x4){0,0,0,0};
      acc[nf] = MFMA(h0, wf2[nf],   acc[nf]);
      acc[nf] = MFMA(h1, wf2[4+nf], acc[nf]);
    }
#pragma unroll
    for (int nf=0;nf<4;++nf)
#pragma unroll
      for (int r=0;r<4;++r){
        const float v = acc[nf][r];
        sumP[nf] += v; sqP[nf] = fmaf(v,v,sqP[nf]);
      }

    cu0=nu0; cu1=nu1; cv0=nv0; cv1=nv1; srcB=srcC;
  }

#pragma unroll
  for (int nf=0;nf<4;++nf){
    float s = sumP[nf], q = sqP[nf];
    s += __shfl_xor(s,16,64); s += __shfl_xor(s,32,64);
    q += __shfl_xor(q,16,64); q += __shfl_xor(q,32,64);
    if (l < 16){ red[w][nf*16+l] = s; red[w][64+nf*16+l] = q; }
  }
  __syncthreads();
  if (t < 128)
    part[(size_t)t*NBLK + blockIdx.x] = red[0][t]+red[1][t]+red[2][t]+red[3][t];
}

// ---- kS3: h1 -> z2 -> BN2+lrelu -> z3 -> segmax -> residual; pipelined -----
__global__ __launch_bounds__(256) void kS3(const unsigned short* __restrict__ Ub,
    const unsigned short* __restrict__ Vb, const int* __restrict__ ei,
    const uint4* __restrict__ wf, const float* __restrict__ coefs2,
    const float* __restrict__ b3, const float* __restrict__ x,
    float* __restrict__ out)
{
  __shared__ __align__(16) unsigned short buf[4][16][72];   // per-wave
  const int t = threadIdx.x, w = t>>6, l = t&63, lr = l&15, lg = l>>4;
  const int G = gridDim.x;

  bf16x8 wf2[8], wf3[8];
#pragma unroll
  for (int f=0;f<8;++f) wf2[f] = asfrag(wf[1024 + f*64 + l]);
#pragma unroll
  for (int f=0;f<8;++f) wf3[f] = asfrag(wf[1536 + f*64 + l]);
  float a2v[4], c2v[4], bb[4];
#pragma unroll
  for (int nf=0;nf<4;++nf){
    a2v[nf]=coefs2[nf*16+lr]; c2v[nf]=coefs2[64+nf*16+lr];
    bb[nf] = b3[nf*16+lr];
  }

  int tile = blockIdx.x;
  int srcB = (tile+G < NTILE) ? ei[(tile+G)*64 + w*16 + lr] : 0;
  bf16x8 cu0,cu1,cv0,cv1;
  {
    const int srcA = ei[tile*64 + w*16 + lr];
    LOADUV(cu0,cu1,cv0,cv1, tile*4+w, srcA)
  }
  for (; tile < NTILE; tile += G){
    const int node = tile*4 + w;
    const int nt = tile + G, nt2 = tile + 2*G;
    const int srcC = (nt2 < NTILE) ? ei[nt2*64 + w*16 + lr] : 0;
    bf16x8 nu0,nu1,nv0,nv1;
    const int nnode = (nt < NTILE) ? nt*4+w : 0;
    LOADUV(nu0,nu1,nv0,nv1, nnode, srcB)

    H1COMP(h0, h1, cu0,cu1,cv0,cv1)

    f32x4 acc2[4];
#pragma unroll
    for (int nf=0;nf<4;++nf){
      acc2[nf] = (f32x4){0,0,0,0};
      acc2[nf] = MFMA(h0, wf2[nf],   acc2[nf]);
      acc2[nf] = MFMA(h1, wf2[4+nf], acc2[nf]);
    }
    // BN2 + lrelu -> per-wave transpose buffer (rows=edges 4lg+r, cols=16nf+lr)
#pragma unroll
    for (int nf=0;nf<4;++nf)
#pragma unroll
      for (int r=0;r<4;++r){
        const float h = lrelu(fmaf(a2v[nf], acc2[nf][r], c2v[nf]));
        buf[w][4*lg+r][16*nf+lr] = f2bf(h);
      }
    const bf16x8 g0 = *(const bf16x8*)&buf[w][lr][8*lg];
    const bf16x8 g1 = *(const bf16x8*)&buf[w][lr][32+8*lg];

    f32x4 acc3[4];
#pragma unroll
    for (int nf=0;nf<4;++nf){
      acc3[nf] = (f32x4){bb[nf],bb[nf],bb[nf],bb[nf]};
      acc3[nf] = MFMA(g0, wf3[nf],   acc3[nf]);
      acc3[nf] = MFMA(g1, wf3[4+nf], acc3[nf]);
    }

#pragma unroll
    for (int nf=0;nf<4;++nf){
      float m = fmaxf(fmaxf(acc3[nf][0],acc3[nf][1]), fmaxf(acc3[nf][2],acc3[nf][3]));
      m = fmaxf(m, __shfl_xor(m,16,64));
      m = fmaxf(m, __shfl_xor(m,32,64));
      if (l < 16){
        const float xv = x[(size_t)node*64 + nf*16 + l];
        out[(size_t)node*64 + nf*16 + l] = lrelu(m + xv);
      }
    }

    cu0=nu0; cu1=nu1; cv0=nv0; cv1=nv1; srcB=srcC;
  }
}

extern "C" void kernel_launch(void* const* d_in, const int* in_sizes, int n_in,
                              void* d_out, int out_size, void* d_ws, size_t ws_size,
                              hipStream_t stream) {
  const float* x   = (const float*)d_in[0];
  const int*   ei  = (const int*)d_in[1];
  const float* W1  = (const float*)d_in[2];
  const float* g1  = (const float*)d_in[4];
  const float* be1 = (const float*)d_in[5];
  const float* W2  = (const float*)d_in[6];
  const float* g2  = (const float*)d_in[8];
  const float* be2 = (const float*)d_in[9];
  const float* W3  = (const float*)d_in[10];
  const float* b3  = (const float*)d_in[11];
  float* out = (float*)d_out;

  // ws: coefs 1KB | part1 1MB | part2 1MB | wfb 32KB | U 6.4MB | V 6.4MB
  float*          coefs = (float*)d_ws;
  float*          part1 = (float*)((char*)d_ws + 1024);
  float*          part2 = part1 + (size_t)NBLK*128;
  unsigned short* wfb   = (unsigned short*)((char*)part2 + (size_t)NBLK*128*4);
  unsigned short* Ub    = (unsigned short*)((char*)wfb + 32768);
  unsigned short* Vb    = Ub + (size_t)N_NODES*64;

  kInit<<<8, 256, 0, stream>>>(W1, W2, W3, wfb);
  kUV<<<(NWT+3)/4, 256, 0, stream>>>(x, (const uint4*)wfb, Ub, Vb);
  kS1<<<NBLK, 256, 0, stream>>>(Ub, Vb, ei, part1);
  kFin<<<64, 256, 0, stream>>>(part1, g1, be1, coefs);
  kScale<<<(N_NODES*8 + 255)/256, 256, 0, stream>>>(Ub, Vb, coefs);
  kS2<<<NBLK, 256, 0, stream>>>(Ub, Vb, ei, (const uint4*)wfb, part2);
  kFin<<<64, 256, 0, stream>>>(part2, g2, be2, coefs + 128);
  kS3<<<NBLK, 256, 0, stream>>>(Ub, Vb, ei, (const uint4*)wfb, coefs + 128,
                                b3, x, out);
}

// Round 9
// 135.600 us; speedup vs baseline: 1.2189x; 1.0023x over previous
//
#include <hip/hip_runtime.h>
#include <hip/hip_bf16.h>

#define N_NODES 50000
#define KNN     16
#define NEDGE   (N_NODES*KNN)     // 800000
#define NTILE   (NEDGE/64)        // 12500 tiles of 64 edges (4 nodes)
#define NWT     (N_NODES/16)      // 3125 wave-tiles for kUV
#define NBLK    2048
#define SLOPE   0.01f
#define EPS     1e-5f

typedef __attribute__((ext_vector_type(8))) short bf16x8;
typedef __attribute__((ext_vector_type(4))) float f32x4;

__device__ __forceinline__ float bfbits(unsigned u){ union{unsigned u;float f;}v; v.u=u; return v.f; }
__device__ __forceinline__ unsigned fbits(float f){ union{float f;unsigned u;}v; v.f=f; return v.u; }
// round-half-up bf16 pair pack: D = {bf16(b) : bf16(a)} via v_perm_b32
__device__ __forceinline__ unsigned pk2(float a, float b){
  const unsigned ua = fbits(a) + 0x8000u;
  const unsigned ub = fbits(b) + 0x8000u;
  return __builtin_amdgcn_perm(ub, ua, 0x07060302u);
}
__device__ __forceinline__ unsigned short f2bfr(float f){
  return (unsigned short)((fbits(f) + 0x8000u) >> 16);
}
__device__ __forceinline__ bf16x8 asfrag(uint4 u){ union{uint4 v; bf16x8 b;}q; q.v=u; return q.b; }
__device__ __forceinline__ f32x4 ld4(const float* p){ return *(const f32x4*)p; }
__device__ __forceinline__ f32x4 MFMA(bf16x8 a, bf16x8 b, f32x4 c){
  return __builtin_amdgcn_mfma_f32_16x16x32_bf16(a, b, c, 0, 0, 0);
}
__device__ __forceinline__ float lrelu(float v){ return v>=0.f ? v : SLOPE*v; }

__device__ __forceinline__ void unp8(bf16x8 v, float* o){
  union{bf16x8 b; unsigned u[4];}q; q.b=v;
#pragma unroll
  for (int w=0;w<4;++w){
    o[2*w]   = bfbits(q.u[w]<<16);
    o[2*w+1] = bfbits(q.u[w]&0xffff0000u);
  }
}
__device__ __forceinline__ bf16x8 pack8r(const float* f){
  union{unsigned u[4]; bf16x8 b;}q;
#pragma unroll
  for (int i=0;i<4;++i) q.u[i] = pk2(f[2*i], f[2*i+1]);
  return q.b;
}
__device__ __forceinline__ bf16x8 pack8v(float4 a, float4 b){
  union{unsigned u[4]; bf16x8 v;}q;
  q.u[0]=pk2(a.x,a.y); q.u[1]=pk2(a.z,a.w);
  q.u[2]=pk2(b.x,b.y); q.u[3]=pk2(b.z,b.w);
  return q.v;
}

// ---- kInit: pack W frags. W1 folded: frags 0..7 = A-B (k 0..63), 8..15 = B -
__global__ __launch_bounds__(256) void kInit(const float* __restrict__ W1,
    const float* __restrict__ W2, const float* __restrict__ W3,
    unsigned short* __restrict__ wf)
{
  const int idx = blockIdx.x*256 + threadIdx.x;   // 2048 entries
  const float* W; int fi; bool fold = false;
  if (idx < 1024)      { W = W1; fi = idx >> 6; fold = (idx < 512); }
  else if (idx < 1536) { W = W2; fi = (idx-1024) >> 6; }
  else                 { W = W3; fi = (idx-1536) >> 6; }
  const int l  = idx & 63;
  const int ks = fi >> 2, nf = fi & 3;
  const int k0 = ks*32 + ((l>>4)<<3);
  const int col = nf*16 + (l&15);
  unsigned short* o = wf + (size_t)idx*8;
#pragma unroll
  for (int e=0;e<8;++e){
    float v = W[(size_t)(k0+e)*64 + col];
    if (fold) v -= W[(size_t)(k0+e+64)*64 + col];
    o[e] = f2bfr(v);
  }
}

// ---- kUV: per-node U = x(A-B), V = xB (bf16) -------------------------------
__global__ __launch_bounds__(256) void kUV(const float* __restrict__ x,
    const uint4* __restrict__ wf, unsigned short* __restrict__ Ub,
    unsigned short* __restrict__ Vb)
{
  const int t = threadIdx.x, w = t>>6, l = t&63, lr = l&15, lg = l>>4;
  const int wt = blockIdx.x*4 + w;
  if (wt >= NWT) return;
  bf16x8 wfr[16];
#pragma unroll
  for (int f=0;f<16;++f) wfr[f] = asfrag(wf[f*64 + l]);
  const int n0 = wt*16;
  const float* xr = x + (size_t)(n0+lr)*64 + lg*8;
  const bf16x8 a0 = pack8v(((const float4*)xr)[0],      ((const float4*)xr)[1]);
  const bf16x8 a1 = pack8v(((const float4*)(xr+32))[0], ((const float4*)(xr+32))[1]);

  f32x4 aU[4], aV[4];
#pragma unroll
  for (int nf=0;nf<4;++nf){
    aU[nf] = (f32x4){0,0,0,0};
    aU[nf] = MFMA(a0, wfr[nf],    aU[nf]);
    aU[nf] = MFMA(a1, wfr[4+nf],  aU[nf]);
    aV[nf] = (f32x4){0,0,0,0};
    aV[nf] = MFMA(a0, wfr[8+nf],  aV[nf]);
    aV[nf] = MFMA(a1, wfr[12+nf], aV[nf]);
  }
#pragma unroll
  for (int nf=0;nf<4;++nf)
#pragma unroll
    for (int r=0;r<4;++r){
      const size_t o = (size_t)(n0 + 4*lg + r)*64 + 16*nf + lr;
      Ub[o] = f2bfr(aU[nf][r]);
      Vb[o] = f2bfr(aV[nf][r]);
    }
}

// load U/V fragments for (nodeId, srcId)
#define LOADUV(U0,U1,V0,V1, nodeId, srcId)                               \
  {                                                                      \
    const unsigned short* Ur = Ub + (size_t)(nodeId)*64 + lg*8;          \
    const unsigned short* Vr = Vb + (size_t)(srcId)*64  + lg*8;          \
    U0 = *(const bf16x8*)Ur; U1 = *(const bf16x8*)(Ur+32);               \
    V0 = *(const bf16x8*)Vr; V1 = *(const bf16x8*)(Vr+32);               \
  }

// ---- kS1: stats of z1 = U[dst] + V[src] (no MFMA), pipelined ---------------
__global__ __launch_bounds__(256) void kS1(const unsigned short* __restrict__ Ub,
    const unsigned short* __restrict__ Vb, const int* __restrict__ ei,
    float* __restrict__ part)
{
  __shared__ float red[4][128];
  const int t = threadIdx.x, w = t>>6, l = t&63, lr = l&15, lg = l>>4;
  const int G = gridDim.x;

  float s[16], q[16];
#pragma unroll
  for (int k=0;k<16;++k){ s[k]=0.f; q[k]=0.f; }

  int tile = blockIdx.x;
  int srcB = (tile+G < NTILE) ? ei[(tile+G)*64 + w*16 + lr] : 0;
  bf16x8 cu0,cu1,cv0,cv1;
  {
    const int srcA = ei[tile*64 + w*16 + lr];
    LOADUV(cu0,cu1,cv0,cv1, tile*4+w, srcA)
  }
  for (; tile < NTILE; tile += G){
    const int nt = tile + G, nt2 = tile + 2*G;
    const int srcC = (nt2 < NTILE) ? ei[nt2*64 + w*16 + lr] : 0;
    bf16x8 nu0,nu1,nv0,nv1;
    const int nnode = (nt < NTILE) ? nt*4+w : 0;
    LOADUV(nu0,nu1,nv0,nv1, nnode, srcB)

    float fu[8], fv[8];
    unp8(cu0,fu); unp8(cv0,fv);
#pragma unroll
    for (int e=0;e<8;++e){ const float z = fu[e]+fv[e]; s[e]+=z; q[e]=fmaf(z,z,q[e]); }
    unp8(cu1,fu); unp8(cv1,fv);
#pragma unroll
    for (int e=0;e<8;++e){ const float z = fu[e]+fv[e]; s[8+e]+=z; q[8+e]=fmaf(z,z,q[8+e]); }

    cu0=nu0; cu1=nu1; cv0=nv0; cv1=nv1; srcB=srcC;
  }

#pragma unroll
  for (int k=0;k<16;++k){
    float a=s[k]; a+=__shfl_xor(a,1,64); a+=__shfl_xor(a,2,64);
    a+=__shfl_xor(a,4,64); a+=__shfl_xor(a,8,64); s[k]=a;
    float b=q[k]; b+=__shfl_xor(b,1,64); b+=__shfl_xor(b,2,64);
    b+=__shfl_xor(b,4,64); b+=__shfl_xor(b,8,64); q[k]=b;
  }
  if (lr == 0){
#pragma unroll
    for (int e=0;e<8;++e){
      red[w][8*lg+e]    = s[e];
      red[w][32+8*lg+e] = s[8+e];
      red[w][64+8*lg+e] = q[e];
      red[w][96+8*lg+e] = q[8+e];
    }
  }
  __syncthreads();
  if (t < 128)
    part[(size_t)t*NBLK + blockIdx.x] = red[0][t]+red[1][t]+red[2][t]+red[3][t];
}

// ---- kFin ------------------------------------------------------------------
__global__ __launch_bounds__(256) void kFin(const float* __restrict__ part,
    const float* __restrict__ g, const float* __restrict__ be,
    float* __restrict__ coefs)
{
  __shared__ float rs[256], rq[256];
  const int c = blockIdx.x, t = threadIdx.x;
  const float* ps = part + (size_t)c*NBLK;
  const float* pq = part + (size_t)(64+c)*NBLK;
  float s = 0.f, q = 0.f;
#pragma unroll
  for (int i=0;i<NBLK/256;++i){ s += ps[t + i*256]; q += pq[t + i*256]; }
  rs[t]=s; rq[t]=q;
  __syncthreads();
#pragma unroll
  for (int off=128; off>0; off>>=1){
    if (t < off){ rs[t]+=rs[t+off]; rq[t]+=rq[t+off]; }
    __syncthreads();
  }
  if (t==0){
    const float inv  = 1.0f/(float)NEDGE;
    const float mean = rs[0]*inv;
    const float var  = rq[0]*inv - mean*mean;
    const float a    = g[c]*rsqrtf(var + EPS);
    coefs[c]      = a;
    coefs[64 + c] = be[c] - mean*a;
  }
}

// ---- kScale: U' = a*U + c ; V' = a*V (in place, fold BN1) ------------------
__global__ __launch_bounds__(256) void kScale(unsigned short* __restrict__ Ub,
    unsigned short* __restrict__ Vb, const float* __restrict__ coefs)
{
  const int j = blockIdx.x*256 + threadIdx.x;     // 400000 jobs of 8 ch
  if (j >= N_NODES*8) return;
  const int c0 = (j & 7)*8;
  float a[8], c[8], f[8];
#pragma unroll
  for (int e=0;e<8;++e){ a[e]=coefs[c0+e]; c[e]=coefs[64+c0+e]; }
  bf16x8 u = ((const bf16x8*)Ub)[j];
  unp8(u,f);
#pragma unroll
  for (int e=0;e<8;++e) f[e] = fmaf(a[e], f[e], c[e]);
  ((bf16x8*)Ub)[j] = pack8r(f);
  bf16x8 v = ((const bf16x8*)Vb)[j];
  unp8(v,f);
#pragma unroll
  for (int e=0;e<8;++e) f[e] *= a[e];
  ((bf16x8*)Vb)[j] = pack8r(f);
}

// h1 fragments from already-loaded U',V' registers
#define H1COMP(h0f, h1f, U0,U1,V0,V1)                                   \
  bf16x8 h0f, h1f;                                                      \
  {                                                                     \
    float fu[8], fv[8], h[8];                                           \
    unp8(U0,fu); unp8(V0,fv);                                           \
    _Pragma("unroll")                                                   \
    for (int e=0;e<8;++e) h[e] = lrelu(fu[e]+fv[e]);                    \
    h0f = pack8r(h);                                                    \
    unp8(U1,fu); unp8(V1,fv);                                           \
    _Pragma("unroll")                                                   \
    for (int e=0;e<8;++e) h[e] = lrelu(fu[e]+fv[e]);                    \
    h1f = pack8r(h);                                                    \
  }

// ---- kS2: h1 = lrelu(U'+V'); z2 = h1@W2; stats2; pipelined -----------------
__global__ __launch_bounds__(256) void kS2(const unsigned short* __restrict__ Ub,
    const unsigned short* __restrict__ Vb, const int* __restrict__ ei,
    const uint4* __restrict__ wf, float* __restrict__ part)
{
  __shared__ float red[4][128];
  const int t = threadIdx.x, w = t>>6, l = t&63, lr = l&15, lg = l>>4;
  const int G = gridDim.x;
  const f32x4 ZERO4 = (f32x4){0.f,0.f,0.f,0.f};

  bf16x8 wf2[8];
#pragma unroll
  for (int f=0;f<8;++f) wf2[f] = asfrag(wf[1024 + f*64 + l]);

  float sumP[4] = {0,0,0,0}, sqP[4] = {0,0,0,0};

  int tile = blockIdx.x;
  int srcB = (tile+G < NTILE) ? ei[(tile+G)*64 + w*16 + lr] : 0;
  bf16x8 cu0,cu1,cv0,cv1;
  {
    const int srcA = ei[tile*64 + w*16 + lr];
    LOADUV(cu0,cu1,cv0,cv1, tile*4+w, srcA)
  }
  for (; tile < NTILE; tile += G){
    const int nt = tile + G, nt2 = tile + 2*G;
    const int srcC = (nt2 < NTILE) ? ei[nt2*64 + w*16 + lr] : 0;
    bf16x8 nu0,nu1,nv0,nv1;
    const int nnode = (nt < NTILE) ? nt*4+w : 0;
    LOADUV(nu0,nu1,nv0,nv1, nnode, srcB)

    H1COMP(h0, h1, cu0,cu1,cv0,cv1)

    f32x4 acc[4];
#pragma unroll
    for (int nf=0;nf<4;++nf){
      acc[nf] = MFMA(h0, wf2[nf],   ZERO4);
      acc[nf] = MFMA(h1, wf2[4+nf], acc[nf]);
    }
#pragma unroll
    for (int nf=0;nf<4;++nf)
#pragma unroll
      for (int r=0;r<4;++r){
        const float v = acc[nf][r];
        sumP[nf] += v; sqP[nf] = fmaf(v,v,sqP[nf]);
      }

    cu0=nu0; cu1=nu1; cv0=nv0; cv1=nv1; srcB=srcC;
  }

#pragma unroll
  for (int nf=0;nf<4;++nf){
    float s = sumP[nf], q = sqP[nf];
    s += __shfl_xor(s,16,64); s += __shfl_xor(s,32,64);
    q += __shfl_xor(q,16,64); q += __shfl_xor(q,32,64);
    if (l < 16){ red[w][nf*16+l] = s; red[w][64+nf*16+l] = q; }
  }
  __syncthreads();
  if (t < 128)
    part[(size_t)t*NBLK + blockIdx.x] = red[0][t]+red[1][t]+red[2][t]+red[3][t];
}

// ---- kS3: h1 -> z2^T (swapped MFMA) -> BN2+lrelu -> z3 -> segmax -> out ----
__global__ __launch_bounds__(256) void kS3(const unsigned short* __restrict__ Ub,
    const unsigned short* __restrict__ Vb, const int* __restrict__ ei,
    const uint4* __restrict__ wf, const float* __restrict__ coefs2,
    const float* __restrict__ b3, const float* __restrict__ x,
    float* __restrict__ out)
{
  __shared__ __align__(16) unsigned short buf[4][16][72];   // per-wave
  const int t = threadIdx.x, w = t>>6, l = t&63, lr = l&15, lg = l>>4;
  const int G = gridDim.x;
  const f32x4 ZERO4 = (f32x4){0.f,0.f,0.f,0.f};

  bf16x8 wf2[8], wf3[8];
#pragma unroll
  for (int f=0;f<8;++f) wf2[f] = asfrag(wf[1024 + f*64 + l]);
#pragma unroll
  for (int f=0;f<8;++f) wf3[f] = asfrag(wf[1536 + f*64 + l]);
  // z2^T lane layout: edge=lr, ch2 = 16nf + 4lg + r  -> vector BN coefs
  f32x4 A2[4], C2[4];
#pragma unroll
  for (int nf=0;nf<4;++nf){
    A2[nf] = ld4(coefs2 + 16*nf + 4*lg);
    C2[nf] = ld4(coefs2 + 64 + 16*nf + 4*lg);
  }
  float bb[4];
#pragma unroll
  for (int nf=0;nf<4;++nf) bb[nf] = b3[nf*16 + lr];

  int tile = blockIdx.x;
  int srcB = (tile+G < NTILE) ? ei[(tile+G)*64 + w*16 + lr] : 0;
  bf16x8 cu0,cu1,cv0,cv1;
  {
    const int srcA = ei[tile*64 + w*16 + lr];
    LOADUV(cu0,cu1,cv0,cv1, tile*4+w, srcA)
  }
  for (; tile < NTILE; tile += G){
    const int node = tile*4 + w;
    const int nt = tile + G, nt2 = tile + 2*G;
    const int srcC = (nt2 < NTILE) ? ei[nt2*64 + w*16 + lr] : 0;
    bf16x8 nu0,nu1,nv0,nv1;
    const int nnode = (nt < NTILE) ? nt*4+w : 0;
    LOADUV(nu0,nu1,nv0,nv1, nnode, srcB)

    H1COMP(h0, h1, cu0,cu1,cv0,cv1)

    // z2^T = W2^T h1^T : same wf2 fragments, operands swapped
    f32x4 acc2[4];
#pragma unroll
    for (int nf=0;nf<4;++nf){
      acc2[nf] = MFMA(wf2[nf],   h0, ZERO4);
      acc2[nf] = MFMA(wf2[4+nf], h1, acc2[nf]);
    }
    // BN2 + lrelu; lane holds edge=lr, chs 16nf+4lg+{0..3} -> packed b64 writes
#pragma unroll
    for (int nf=0;nf<4;++nf){
      const float t0 = lrelu(fmaf(A2[nf][0], acc2[nf][0], C2[nf][0]));
      const float t1 = lrelu(fmaf(A2[nf][1], acc2[nf][1], C2[nf][1]));
      const float t2 = lrelu(fmaf(A2[nf][2], acc2[nf][2], C2[nf][2]));
      const float t3 = lrelu(fmaf(A2[nf][3], acc2[nf][3], C2[nf][3]));
      *(uint2*)&buf[w][lr][16*nf + 4*lg] = make_uint2(pk2(t0,t1), pk2(t2,t3));
    }
    // read A-frags: h2[edge=lr][ch2 8lg.. / 32+8lg..] (same-wave LDS, in-order)
    const bf16x8 g0 = *(const bf16x8*)&buf[w][lr][8*lg];
    const bf16x8 g1 = *(const bf16x8*)&buf[w][lr][32+8*lg];

    f32x4 acc3[4];
#pragma unroll
    for (int nf=0;nf<4;++nf){
      acc3[nf] = MFMA(g0, wf3[nf],   ZERO4);
      acc3[nf] = MFMA(g1, wf3[4+nf], acc3[nf]);
    }

    // segmax over node's 16 edges; bias after max; residual
#pragma unroll
    for (int nf=0;nf<4;++nf){
      float m = fmaxf(fmaxf(acc3[nf][0],acc3[nf][1]), fmaxf(acc3[nf][2],acc3[nf][3]));
      m = fmaxf(m, __shfl_xor(m,16,64));
      m = fmaxf(m, __shfl_xor(m,32,64));
      if (l < 16){
        const float xv = x[(size_t)node*64 + nf*16 + l];
        out[(size_t)node*64 + nf*16 + l] = lrelu(m + bb[nf] + xv);
      }
    }

    cu0=nu0; cu1=nu1; cv0=nv0; cv1=nv1; srcB=srcC;
  }
}

extern "C" void kernel_launch(void* const* d_in, const int* in_sizes, int n_in,
                              void* d_out, int out_size, void* d_ws, size_t ws_size,
                              hipStream_t stream) {
  const float* x   = (const float*)d_in[0];
  const int*   ei  = (const int*)d_in[1];
  const float* W1  = (const float*)d_in[2];
  const float* g1  = (const float*)d_in[4];
  const float* be1 = (const float*)d_in[5];
  const float* W2  = (const float*)d_in[6];
  const float* g2  = (const float*)d_in[8];
  const float* be2 = (const float*)d_in[9];
  const float* W3  = (const float*)d_in[10];
  const float* b3  = (const float*)d_in[11];
  float* out = (float*)d_out;

  // ws: coefs 1KB | part1 1MB | part2 1MB | wfb 32KB | U 6.4MB | V 6.4MB
  float*          coefs = (float*)d_ws;
  float*          part1 = (float*)((char*)d_ws + 1024);
  float*          part2 = part1 + (size_t)NBLK*128;
  unsigned short* wfb   = (unsigned short*)((char*)part2 + (size_t)NBLK*128*4);
  unsigned short* Ub    = (unsigned short*)((char*)wfb + 32768);
  unsigned short* Vb    = Ub + (size_t)N_NODES*64;

  kInit<<<8, 256, 0, stream>>>(W1, W2, W3, wfb);
  kUV<<<(NWT+3)/4, 256, 0, stream>>>(x, (const uint4*)wfb, Ub, Vb);
  kS1<<<NBLK, 256, 0, stream>>>(Ub, Vb, ei, part1);
  kFin<<<64, 256, 0, stream>>>(part1, g1, be1, coefs);
  kScale<<<(N_NODES*8 + 255)/256, 256, 0, stream>>>(Ub, Vb, coefs);
  kS2<<<NBLK, 256, 0, stream>>>(Ub, Vb, ei, (const uint4*)wfb, part2);
  kFin<<<64, 256, 0, stream>>>(part2, g2, be2, coefs + 128);
  kS3<<<NBLK, 256, 0, stream>>>(Ub, Vb, ei, (const uint4*)wfb, coefs + 128,
                                b3, x, out);
}

// Round 10
// 117.034 us; speedup vs baseline: 1.4123x; 1.1586x over previous
//
#include <hip/hip_runtime.h>
#include <hip/hip_bf16.h>

#define N_NODES 50000
#define KNN     16
#define NEDGE   (N_NODES*KNN)     // 800000
#define NTILE   (NEDGE/64)        // 12500 tiles of 64 edges  (kS1)
#define NTILE2  (NEDGE/128)       // 6250 tiles of 128 edges  (kS2/kS3, 8 nodes)
#define NWT     (N_NODES/16)      // 3125 wave-tiles for kUV
#define NB1     2048              // grid kS1
#define NB2     1024              // grid kS2/kS3
#define SLOPE   0.01f
#define EPS     1e-5f

typedef __attribute__((ext_vector_type(8))) short bf16x8;
typedef __attribute__((ext_vector_type(4))) float f32x4;

__device__ __forceinline__ float bfbits(unsigned u){ union{unsigned u;float f;}v; v.u=u; return v.f; }
__device__ __forceinline__ unsigned fbits(float f){ union{float f;unsigned u;}v; v.f=f; return v.u; }
__device__ __forceinline__ unsigned pk2(float a, float b){
  const unsigned ua = fbits(a) + 0x8000u;
  const unsigned ub = fbits(b) + 0x8000u;
  return __builtin_amdgcn_perm(ub, ua, 0x07060302u);
}
__device__ __forceinline__ unsigned short f2bfr(float f){
  return (unsigned short)((fbits(f) + 0x8000u) >> 16);
}
__device__ __forceinline__ bf16x8 asfrag(uint4 u){ union{uint4 v; bf16x8 b;}q; q.v=u; return q.b; }
__device__ __forceinline__ f32x4 MFMA(bf16x8 a, bf16x8 b, f32x4 c){
  return __builtin_amdgcn_mfma_f32_16x16x32_bf16(a, b, c, 0, 0, 0);
}
__device__ __forceinline__ float lrelu(float v){ return v>=0.f ? v : SLOPE*v; }

__device__ __forceinline__ void unp8(bf16x8 v, float* o){
  union{bf16x8 b; unsigned u[4];}q; q.b=v;
#pragma unroll
  for (int w=0;w<4;++w){
    o[2*w]   = bfbits(q.u[w]<<16);
    o[2*w+1] = bfbits(q.u[w]&0xffff0000u);
  }
}
__device__ __forceinline__ bf16x8 pack8r(const float* f){
  union{unsigned u[4]; bf16x8 b;}q;
#pragma unroll
  for (int i=0;i<4;++i) q.u[i] = pk2(f[2*i], f[2*i+1]);
  return q.b;
}
__device__ __forceinline__ bf16x8 pack8v(float4 a, float4 b){
  union{unsigned u[4]; bf16x8 v;}q;
  q.u[0]=pk2(a.x,a.y); q.u[1]=pk2(a.z,a.w);
  q.u[2]=pk2(b.x,b.y); q.u[3]=pk2(b.z,b.w);
  return q.v;
}

// ---- kInit: pack W frags. W1 folded: frags 0..7 = A-B, 8..15 = B -----------
__global__ __launch_bounds__(256) void kInit(const float* __restrict__ W1,
    const float* __restrict__ W2, const float* __restrict__ W3,
    unsigned short* __restrict__ wf)
{
  const int idx = blockIdx.x*256 + threadIdx.x;   // 2048 entries
  const float* W; int fi; bool fold = false;
  if (idx < 1024)      { W = W1; fi = idx >> 6; fold = (idx < 512); }
  else if (idx < 1536) { W = W2; fi = (idx-1024) >> 6; }
  else                 { W = W3; fi = (idx-1536) >> 6; }
  const int l  = idx & 63;
  const int ks = fi >> 2, nf = fi & 3;
  const int k0 = ks*32 + ((l>>4)<<3);
  const int col = nf*16 + (l&15);
  unsigned short* o = wf + (size_t)idx*8;
#pragma unroll
  for (int e=0;e<8;++e){
    float v = W[(size_t)(k0+e)*64 + col];
    if (fold) v -= W[(size_t)(k0+e+64)*64 + col];
    o[e] = f2bfr(v);
  }
}

// ---- kUV: per-node U = x(A-B), V = xB (bf16) -------------------------------
__global__ __launch_bounds__(256) void kUV(const float* __restrict__ x,
    const uint4* __restrict__ wf, unsigned short* __restrict__ Ub,
    unsigned short* __restrict__ Vb)
{
  const int t = threadIdx.x, w = t>>6, l = t&63, lr = l&15, lg = l>>4;
  const int wt = blockIdx.x*4 + w;
  if (wt >= NWT) return;
  bf16x8 wfr[16];
#pragma unroll
  for (int f=0;f<16;++f) wfr[f] = asfrag(wf[f*64 + l]);
  const int n0 = wt*16;
  const float* xr = x + (size_t)(n0+lr)*64 + lg*8;
  const bf16x8 a0 = pack8v(((const float4*)xr)[0],      ((const float4*)xr)[1]);
  const bf16x8 a1 = pack8v(((const float4*)(xr+32))[0], ((const float4*)(xr+32))[1]);

  f32x4 aU[4], aV[4];
#pragma unroll
  for (int nf=0;nf<4;++nf){
    aU[nf] = (f32x4){0,0,0,0};
    aU[nf] = MFMA(a0, wfr[nf],    aU[nf]);
    aU[nf] = MFMA(a1, wfr[4+nf],  aU[nf]);
    aV[nf] = (f32x4){0,0,0,0};
    aV[nf] = MFMA(a0, wfr[8+nf],  aV[nf]);
    aV[nf] = MFMA(a1, wfr[12+nf], aV[nf]);
  }
#pragma unroll
  for (int nf=0;nf<4;++nf)
#pragma unroll
    for (int r=0;r<4;++r){
      const size_t o = (size_t)(n0 + 4*lg + r)*64 + 16*nf + lr;
      Ub[o] = f2bfr(aU[nf][r]);
      Vb[o] = f2bfr(aV[nf][r]);
    }
}

#define LOADUV(U0,U1,V0,V1, nodeId, srcId)                               \
  {                                                                      \
    const unsigned short* Ur = Ub + (size_t)(nodeId)*64 + lg*8;          \
    const unsigned short* Vr = Vb + (size_t)(srcId)*64  + lg*8;          \
    U0 = *(const bf16x8*)(Ur); U1 = *(const bf16x8*)(Ur + 32);           \
    V0 = *(const bf16x8*)(Vr); V1 = *(const bf16x8*)(Vr + 32);           \
  }

#define H1COMP(h0f, h1f, U0,U1,V0,V1)                                   \
  bf16x8 h0f, h1f;                                                      \
  {                                                                     \
    float fu[8], fv[8], h[8];                                           \
    unp8(U0,fu); unp8(V0,fv);                                           \
    _Pragma("unroll")                                                   \
    for (int e=0;e<8;++e) h[e] = lrelu(fu[e]+fv[e]);                    \
    h0f = pack8r(h);                                                    \
    unp8(U1,fu); unp8(V1,fv);                                           \
    _Pragma("unroll")                                                   \
    for (int e=0;e<8;++e) h[e] = lrelu(fu[e]+fv[e]);                    \
    h1f = pack8r(h);                                                    \
  }

// ---- kS1: stats of z1 = U[dst] + V[src] (no MFMA), pipelined ---------------
__global__ __launch_bounds__(256) void kS1(const unsigned short* __restrict__ Ub,
    const unsigned short* __restrict__ Vb, const int* __restrict__ ei,
    float* __restrict__ part)
{
  __shared__ float red[4][128];
  const int t = threadIdx.x, w = t>>6, l = t&63, lr = l&15, lg = l>>4;
  const int G = gridDim.x;

  float s[16], q[16];
#pragma unroll
  for (int k=0;k<16;++k){ s[k]=0.f; q[k]=0.f; }

  int tile = blockIdx.x;
  int srcB = (tile+G < NTILE) ? ei[(tile+G)*64 + w*16 + lr] : 0;
  bf16x8 cu0,cu1,cv0,cv1;
  {
    const int srcA = ei[tile*64 + w*16 + lr];
    LOADUV(cu0,cu1,cv0,cv1, tile*4+w, srcA)
  }
  for (; tile < NTILE; tile += G){
    const int nt = tile + G, nt2 = tile + 2*G;
    const int srcC = (nt2 < NTILE) ? ei[nt2*64 + w*16 + lr] : 0;
    bf16x8 nu0,nu1,nv0,nv1;
    const int nnode = (nt < NTILE) ? nt*4+w : 0;
    LOADUV(nu0,nu1,nv0,nv1, nnode, srcB)

    float fu[8], fv[8];
    unp8(cu0,fu); unp8(cv0,fv);
#pragma unroll
    for (int e=0;e<8;++e){ const float z = fu[e]+fv[e]; s[e]+=z; q[e]=fmaf(z,z,q[e]); }
    unp8(cu1,fu); unp8(cv1,fv);
#pragma unroll
    for (int e=0;e<8;++e){ const float z = fu[e]+fv[e]; s[8+e]+=z; q[8+e]=fmaf(z,z,q[8+e]); }

    cu0=nu0; cu1=nu1; cv0=nv0; cv1=nv1; srcB=srcC;
  }

#pragma unroll
  for (int k=0;k<16;++k){
    float a=s[k]; a+=__shfl_xor(a,1,64); a+=__shfl_xor(a,2,64);
    a+=__shfl_xor(a,4,64); a+=__shfl_xor(a,8,64); s[k]=a;
    float b=q[k]; b+=__shfl_xor(b,1,64); b+=__shfl_xor(b,2,64);
    b+=__shfl_xor(b,4,64); b+=__shfl_xor(b,8,64); q[k]=b;
  }
  if (lr == 0){
#pragma unroll
    for (int e=0;e<8;++e){
      red[w][8*lg+e]    = s[e];
      red[w][32+8*lg+e] = s[8+e];
      red[w][64+8*lg+e] = q[e];
      red[w][96+8*lg+e] = q[8+e];
    }
  }
  __syncthreads();
  if (t < 128)
    part[(size_t)t*NB1 + blockIdx.x] = red[0][t]+red[1][t]+red[2][t]+red[3][t];
}

// ---- kFin: 64 blocks, block c reduces sum/sq rows over nb entries ----------
__global__ __launch_bounds__(256) void kFin(const float* __restrict__ part,
    const float* __restrict__ g, const float* __restrict__ be,
    float* __restrict__ coefs, int nb)
{
  __shared__ float rs[256], rq[256];
  const int c = blockIdx.x, t = threadIdx.x;
  const float* ps = part + (size_t)c*nb;
  const float* pq = part + (size_t)(64+c)*nb;
  float s = 0.f, q = 0.f;
  for (int i=t; i<nb; i+=256){ s += ps[i]; q += pq[i]; }
  rs[t]=s; rq[t]=q;
  __syncthreads();
#pragma unroll
  for (int off=128; off>0; off>>=1){
    if (t < off){ rs[t]+=rs[t+off]; rq[t]+=rq[t+off]; }
    __syncthreads();
  }
  if (t==0){
    const float inv  = 1.0f/(float)NEDGE;
    const float mean = rs[0]*inv;
    const float var  = rq[0]*inv - mean*mean;
    const float a    = g[c]*rsqrtf(var + EPS);
    coefs[c]      = a;
    coefs[64 + c] = be[c] - mean*a;
  }
}

// ---- kScale: U' = a*U + c ; V' = a*V (in place, fold BN1) ------------------
__global__ __launch_bounds__(256) void kScale(unsigned short* __restrict__ Ub,
    unsigned short* __restrict__ Vb, const float* __restrict__ coefs)
{
  const int j = blockIdx.x*256 + threadIdx.x;
  if (j >= N_NODES*8) return;
  const int c0 = (j & 7)*8;
  float a[8], c[8], f[8];
#pragma unroll
  for (int e=0;e<8;++e){ a[e]=coefs[c0+e]; c[e]=coefs[64+c0+e]; }
  bf16x8 u = ((const bf16x8*)Ub)[j];
  unp8(u,f);
#pragma unroll
  for (int e=0;e<8;++e) f[e] = fmaf(a[e], f[e], c[e]);
  ((bf16x8*)Ub)[j] = pack8r(f);
  bf16x8 v = ((const bf16x8*)Vb)[j];
  unp8(v,f);
#pragma unroll
  for (int e=0;e<8;++e) f[e] *= a[e];
  ((bf16x8*)Vb)[j] = pack8r(f);
}

// ---- kS2: 2-node ILP; h1 = lrelu(U'+V'); z2 = h1@W2; stats2 ----------------
__global__ __launch_bounds__(256,4) void kS2(const unsigned short* __restrict__ Ub,
    const unsigned short* __restrict__ Vb, const int* __restrict__ ei,
    const uint4* __restrict__ wfg, float* __restrict__ part)
{
  __shared__ uint4 wlds[512];          // wf2 table, 8 KB
  __shared__ float red[4][128];
  const int t = threadIdx.x, w = t>>6, l = t&63, lr = l&15, lg = l>>4;
  const int G = gridDim.x;
  const f32x4 Z4 = (f32x4){0.f,0.f,0.f,0.f};

  for (int i=t; i<512; i+=256) wlds[i] = wfg[1024+i];
  __syncthreads();

  float sumP[4] = {0,0,0,0}, sqP[4] = {0,0,0,0};

  int tile = blockIdx.x;
  int srcA = ei[tile*128 + (2*w)*16 + lr];
  int srcB = ei[tile*128 + (2*w+1)*16 + lr];
  for (; tile < NTILE2; tile += G){
    const int nA = tile*8 + 2*w, nB = nA + 1;
    bf16x8 uA0,uA1,vA0,vA1, uB0,uB1,vB0,vB1;
    LOADUV(uA0,uA1,vA0,vA1, nA, srcA)
    LOADUV(uB0,uB1,vB0,vB1, nB, srcB)
    const int nt = tile + G;
    if (nt < NTILE2){
      srcA = ei[nt*128 + (2*w)*16 + lr];
      srcB = ei[nt*128 + (2*w+1)*16 + lr];
    }

    H1COMP(hA0, hA1, uA0,uA1,vA0,vA1)
    H1COMP(hB0, hB1, uB0,uB1,vB0,vB1)

    f32x4 aA[4], aB[4];
#pragma unroll
    for (int nf=0;nf<4;++nf){
      const bf16x8 b0 = asfrag(wlds[nf*64 + l]);
      const bf16x8 b1 = asfrag(wlds[(4+nf)*64 + l]);
      aA[nf] = MFMA(hA0, b0, Z4);  aA[nf] = MFMA(hA1, b1, aA[nf]);
      aB[nf] = MFMA(hB0, b0, Z4);  aB[nf] = MFMA(hB1, b1, aB[nf]);
    }
#pragma unroll
    for (int nf=0;nf<4;++nf)
#pragma unroll
      for (int r=0;r<4;++r){
        const float v0 = aA[nf][r], v1 = aB[nf][r];
        sumP[nf] += v0 + v1;
        sqP[nf] = fmaf(v0,v0,sqP[nf]);
        sqP[nf] = fmaf(v1,v1,sqP[nf]);
      }
  }

#pragma unroll
  for (int nf=0;nf<4;++nf){
    float s = sumP[nf], q = sqP[nf];
    s += __shfl_xor(s,16,64); s += __shfl_xor(s,32,64);
    q += __shfl_xor(q,16,64); q += __shfl_xor(q,32,64);
    if (l < 16){ red[w][nf*16+l] = s; red[w][64+nf*16+l] = q; }
  }
  __syncthreads();
  if (t < 128)
    part[(size_t)t*NB2 + blockIdx.x] = red[0][t]+red[1][t]+red[2][t]+red[3][t];
}

// ---- kS3: 2-node ILP; h1 -> z2 -> BN2+lrelu -> z3 -> segmax -> out ---------
__global__ __launch_bounds__(256,4) void kS3(const unsigned short* __restrict__ Ub,
    const unsigned short* __restrict__ Vb, const int* __restrict__ ei,
    const uint4* __restrict__ wfg, const float* __restrict__ coefs2,
    const float* __restrict__ b3, const float* __restrict__ x,
    float* __restrict__ out)
{
  __shared__ uint4 wlds[1024];                              // wf2|wf3, 16 KB
  __shared__ __align__(16) unsigned short buf[8][16][72];   // per-stream, 18 KB
  const int t = threadIdx.x, w = t>>6, l = t&63, lr = l&15, lg = l>>4;
  const int G = gridDim.x;
  const f32x4 Z4 = (f32x4){0.f,0.f,0.f,0.f};

  for (int i=t; i<1024; i+=256) wlds[i] = wfg[1024+i];
  __syncthreads();

  float a2v[4], c2v[4], bb[4];
#pragma unroll
  for (int nf=0;nf<4;++nf){
    a2v[nf]=coefs2[nf*16+lr]; c2v[nf]=coefs2[64+nf*16+lr];
    bb[nf] = b3[nf*16+lr];
  }

  int tile = blockIdx.x;
  int srcA = ei[tile*128 + (2*w)*16 + lr];
  int srcB = ei[tile*128 + (2*w+1)*16 + lr];
  for (; tile < NTILE2; tile += G){
    const int nA = tile*8 + 2*w, nB = nA + 1;
    bf16x8 uA0,uA1,vA0,vA1, uB0,uB1,vB0,vB1;
    LOADUV(uA0,uA1,vA0,vA1, nA, srcA)
    LOADUV(uB0,uB1,vB0,vB1, nB, srcB)
    const int nt = tile + G;
    if (nt < NTILE2){
      srcA = ei[nt*128 + (2*w)*16 + lr];
      srcB = ei[nt*128 + (2*w+1)*16 + lr];
    }

    H1COMP(hA0, hA1, uA0,uA1,vA0,vA1)
    H1COMP(hB0, hB1, uB0,uB1,vB0,vB1)

    // GEMM2 (unswapped): D = z2[edge 4lg+r][ch 16nf+lr]; B shared across streams
    f32x4 aA[4], aB[4];
#pragma unroll
    for (int nf=0;nf<4;++nf){
      const bf16x8 b0 = asfrag(wlds[nf*64 + l]);
      const bf16x8 b1 = asfrag(wlds[(4+nf)*64 + l]);
      aA[nf] = MFMA(hA0, b0, Z4);  aA[nf] = MFMA(hA1, b1, aA[nf]);
      aB[nf] = MFMA(hB0, b0, Z4);  aB[nf] = MFMA(hB1, b1, aB[nf]);
    }
    // BN2 + lrelu -> per-stream transpose buffers
#pragma unroll
    for (int nf=0;nf<4;++nf)
#pragma unroll
      for (int r=0;r<4;++r){
        buf[2*w  ][4*lg+r][16*nf+lr] = f2bfr(lrelu(fmaf(a2v[nf], aA[nf][r], c2v[nf])));
        buf[2*w+1][4*lg+r][16*nf+lr] = f2bfr(lrelu(fmaf(a2v[nf], aB[nf][r], c2v[nf])));
      }
    const bf16x8 gA0 = *(const bf16x8*)&buf[2*w  ][lr][8*lg];
    const bf16x8 gA1 = *(const bf16x8*)&buf[2*w  ][lr][32+8*lg];
    const bf16x8 gB0 = *(const bf16x8*)&buf[2*w+1][lr][8*lg];
    const bf16x8 gB1 = *(const bf16x8*)&buf[2*w+1][lr][32+8*lg];

    f32x4 cA[4], cB[4];
#pragma unroll
    for (int nf=0;nf<4;++nf){
      const bf16x8 b0 = asfrag(wlds[512 + nf*64 + l]);
      const bf16x8 b1 = asfrag(wlds[512 + (4+nf)*64 + l]);
      cA[nf] = MFMA(gA0, b0, Z4);  cA[nf] = MFMA(gA1, b1, cA[nf]);
      cB[nf] = MFMA(gB0, b0, Z4);  cB[nf] = MFMA(gB1, b1, cB[nf]);
    }

    // segmax over each node's 16 edges; bias after max; residual
#pragma unroll
    for (int nf=0;nf<4;++nf){
      float mA = fmaxf(fmaxf(cA[nf][0],cA[nf][1]), fmaxf(cA[nf][2],cA[nf][3]));
      mA = fmaxf(mA, __shfl_xor(mA,16,64));
      mA = fmaxf(mA, __shfl_xor(mA,32,64));
      float mB = fmaxf(fmaxf(cB[nf][0],cB[nf][1]), fmaxf(cB[nf][2],cB[nf][3]));
      mB = fmaxf(mB, __shfl_xor(mB,16,64));
      mB = fmaxf(mB, __shfl_xor(mB,32,64));
      if (l < 16){
        const float xA = x[(size_t)nA*64 + nf*16 + l];
        out[(size_t)nA*64 + nf*16 + l] = lrelu(mA + bb[nf] + xA);
        const float xB = x[(size_t)nB*64 + nf*16 + l];
        out[(size_t)nB*64 + nf*16 + l] = lrelu(mB + bb[nf] + xB);
      }
    }
  }
}

extern "C" void kernel_launch(void* const* d_in, const int* in_sizes, int n_in,
                              void* d_out, int out_size, void* d_ws, size_t ws_size,
                              hipStream_t stream) {
  const float* x   = (const float*)d_in[0];
  const int*   ei  = (const int*)d_in[1];
  const float* W1  = (const float*)d_in[2];
  const float* g1  = (const float*)d_in[4];
  const float* be1 = (const float*)d_in[5];
  const float* W2  = (const float*)d_in[6];
  const float* g2  = (const float*)d_in[8];
  const float* be2 = (const float*)d_in[9];
  const float* W3  = (const float*)d_in[10];
  const float* b3  = (const float*)d_in[11];
  float* out = (float*)d_out;

  // ws: coefs 1KB | part1 1MB | part2 512KB | wfb 32KB | U 6.4MB | V 6.4MB
  float*          coefs = (float*)d_ws;
  float*          part1 = (float*)((char*)d_ws + 1024);
  float*          part2 = part1 + (size_t)NB1*128;
  unsigned short* wfb   = (unsigned short*)((char*)part2 + (size_t)NB2*128*4);
  unsigned short* Ub    = (unsigned short*)((char*)wfb + 32768);
  unsigned short* Vb    = Ub + (size_t)N_NODES*64;

  kInit<<<8, 256, 0, stream>>>(W1, W2, W3, wfb);
  kUV<<<(NWT+3)/4, 256, 0, stream>>>(x, (const uint4*)wfb, Ub, Vb);
  kS1<<<NB1, 256, 0, stream>>>(Ub, Vb, ei, part1);
  kFin<<<64, 256, 0, stream>>>(part1, g1, be1, coefs, NB1);
  kScale<<<(N_NODES*8 + 255)/256, 256, 0, stream>>>(Ub, Vb, coefs);
  kS2<<<NB2, 256, 0, stream>>>(Ub, Vb, ei, (const uint4*)wfb, part2);
  kFin<<<64, 256, 0, stream>>>(part2, g2, be2, coefs + 128, NB2);
  kS3<<<NB2, 256, 0, stream>>>(Ub, Vb, ei, (const uint4*)wfb, coefs + 128,
                               b3, x, out);
}

// Round 11
// 111.398 us; speedup vs baseline: 1.4838x; 1.0506x over previous
//
#include <hip/hip_runtime.h>
#include <hip/hip_bf16.h>

#define N_NODES 50000
#define KNN     16
#define NEDGE   (N_NODES*KNN)     // 800000
#define NTILE2  (NEDGE/128)       // 6250 tiles of 128 edges (8 nodes)
#define NWT     (N_NODES/16)      // 3125 wave-tiles for kUV
#define NB2     1024              // grid kS1/kS2/kS3
#define SLOPE   0.01f
#define EPS     1e-5f

typedef __attribute__((ext_vector_type(8))) short bf16x8;
typedef __attribute__((ext_vector_type(4))) float f32x4;

__device__ __forceinline__ float bfbits(unsigned u){ union{unsigned u;float f;}v; v.u=u; return v.f; }
__device__ __forceinline__ unsigned fbits(float f){ union{float f;unsigned u;}v; v.f=f; return v.u; }
__device__ __forceinline__ unsigned pk2(float a, float b){
  const unsigned ua = fbits(a) + 0x8000u;
  const unsigned ub = fbits(b) + 0x8000u;
  return __builtin_amdgcn_perm(ub, ua, 0x07060302u);
}
__device__ __forceinline__ unsigned short f2bfr(float f){
  return (unsigned short)((fbits(f) + 0x8000u) >> 16);
}
__device__ __forceinline__ bf16x8 asfrag(uint4 u){ union{uint4 v; bf16x8 b;}q; q.v=u; return q.b; }
__device__ __forceinline__ f32x4 MFMA(bf16x8 a, bf16x8 b, f32x4 c){
  return __builtin_amdgcn_mfma_f32_16x16x32_bf16(a, b, c, 0, 0, 0);
}
__device__ __forceinline__ float lrelu(float v){ return v>=0.f ? v : SLOPE*v; }

__device__ __forceinline__ void unp8(bf16x8 v, float* o){
  union{bf16x8 b; unsigned u[4];}q; q.b=v;
#pragma unroll
  for (int w=0;w<4;++w){
    o[2*w]   = bfbits(q.u[w]<<16);
    o[2*w+1] = bfbits(q.u[w]&0xffff0000u);
  }
}
__device__ __forceinline__ bf16x8 pack8r(const float* f){
  union{unsigned u[4]; bf16x8 b;}q;
#pragma unroll
  for (int i=0;i<4;++i) q.u[i] = pk2(f[2*i], f[2*i+1]);
  return q.b;
}
__device__ __forceinline__ bf16x8 pack8v(float4 a, float4 b){
  union{unsigned u[4]; bf16x8 v;}q;
  q.u[0]=pk2(a.x,a.y); q.u[1]=pk2(a.z,a.w);
  q.u[2]=pk2(b.x,b.y); q.u[3]=pk2(b.z,b.w);
  return q.v;
}

// ---- kInit: pack W frags. W1 folded: frags 0..7 = A-B, 8..15 = B -----------
__global__ __launch_bounds__(256) void kInit(const float* __restrict__ W1,
    const float* __restrict__ W2, const float* __restrict__ W3,
    unsigned short* __restrict__ wf)
{
  const int idx = blockIdx.x*256 + threadIdx.x;   // 2048 entries
  const float* W; int fi; bool fold = false;
  if (idx < 1024)      { W = W1; fi = idx >> 6; fold = (idx < 512); }
  else if (idx < 1536) { W = W2; fi = (idx-1024) >> 6; }
  else                 { W = W3; fi = (idx-1536) >> 6; }
  const int l  = idx & 63;
  const int ks = fi >> 2, nf = fi & 3;
  const int k0 = ks*32 + ((l>>4)<<3);
  const int col = nf*16 + (l&15);
  unsigned short* o = wf + (size_t)idx*8;
#pragma unroll
  for (int e=0;e<8;++e){
    float v = W[(size_t)(k0+e)*64 + col];
    if (fold) v -= W[(size_t)(k0+e+64)*64 + col];
    o[e] = f2bfr(v);
  }
}

// ---- kUV: per-node U = x(A-B), V = xB (bf16) -------------------------------
__global__ __launch_bounds__(256) void kUV(const float* __restrict__ x,
    const uint4* __restrict__ wf, unsigned short* __restrict__ Ub,
    unsigned short* __restrict__ Vb)
{
  const int t = threadIdx.x, w = t>>6, l = t&63, lr = l&15, lg = l>>4;
  const int wt = blockIdx.x*4 + w;
  if (wt >= NWT) return;
  bf16x8 wfr[16];
#pragma unroll
  for (int f=0;f<16;++f) wfr[f] = asfrag(wf[f*64 + l]);
  const int n0 = wt*16;
  const float* xr = x + (size_t)(n0+lr)*64 + lg*8;
  const bf16x8 a0 = pack8v(((const float4*)xr)[0],      ((const float4*)xr)[1]);
  const bf16x8 a1 = pack8v(((const float4*)(xr+32))[0], ((const float4*)(xr+32))[1]);

  f32x4 aU[4], aV[4];
#pragma unroll
  for (int nf=0;nf<4;++nf){
    aU[nf] = (f32x4){0,0,0,0};
    aU[nf] = MFMA(a0, wfr[nf],    aU[nf]);
    aU[nf] = MFMA(a1, wfr[4+nf],  aU[nf]);
    aV[nf] = (f32x4){0,0,0,0};
    aV[nf] = MFMA(a0, wfr[8+nf],  aV[nf]);
    aV[nf] = MFMA(a1, wfr[12+nf], aV[nf]);
  }
#pragma unroll
  for (int nf=0;nf<4;++nf)
#pragma unroll
    for (int r=0;r<4;++r){
      const size_t o = (size_t)(n0 + 4*lg + r)*64 + 16*nf + lr;
      Ub[o] = f2bfr(aU[nf][r]);
      Vb[o] = f2bfr(aV[nf][r]);
    }
}

#define LOADUV(U0,U1,V0,V1, nodeId, srcId)                               \
  {                                                                      \
    const unsigned short* Ur = Ub + (size_t)(nodeId)*64 + lg*8;          \
    const unsigned short* Vr = Vb + (size_t)(srcId)*64  + lg*8;          \
    U0 = *(const bf16x8*)(Ur); U1 = *(const bf16x8*)(Ur + 32);           \
    V0 = *(const bf16x8*)(Vr); V1 = *(const bf16x8*)(Vr + 32);           \
  }

#define H1COMP(h0f, h1f, U0,U1,V0,V1)                                   \
  bf16x8 h0f, h1f;                                                      \
  {                                                                     \
    float fu[8], fv[8], h[8];                                           \
    unp8(U0,fu); unp8(V0,fv);                                           \
    _Pragma("unroll")                                                   \
    for (int e=0;e<8;++e) h[e] = lrelu(fu[e]+fv[e]);                    \
    h0f = pack8r(h);                                                    \
    unp8(U1,fu); unp8(V1,fv);                                           \
    _Pragma("unroll")                                                   \
    for (int e=0;e<8;++e) h[e] = lrelu(fu[e]+fv[e]);                    \
    h1f = pack8r(h);                                                    \
  }

// ---- kS1: 2-node ILP; stats of z1 = U[dst] + V[src] (no MFMA) --------------
__global__ __launch_bounds__(256,4) void kS1(const unsigned short* __restrict__ Ub,
    const unsigned short* __restrict__ Vb, const int* __restrict__ ei,
    float* __restrict__ part)
{
  __shared__ float red[4][128];
  const int t = threadIdx.x, w = t>>6, l = t&63, lr = l&15, lg = l>>4;
  const int G = gridDim.x;

  float s[16], q[16];
#pragma unroll
  for (int k=0;k<16;++k){ s[k]=0.f; q[k]=0.f; }

  int tile = blockIdx.x;
  int srcA = ei[tile*128 + (2*w)*16 + lr];
  int srcB = ei[tile*128 + (2*w+1)*16 + lr];
  for (; tile < NTILE2; tile += G){
    const int nA = tile*8 + 2*w, nB = nA + 1;
    bf16x8 uA0,uA1,vA0,vA1, uB0,uB1,vB0,vB1;
    LOADUV(uA0,uA1,vA0,vA1, nA, srcA)
    LOADUV(uB0,uB1,vB0,vB1, nB, srcB)
    const int nt = tile + G;
    if (nt < NTILE2){
      srcA = ei[nt*128 + (2*w)*16 + lr];
      srcB = ei[nt*128 + (2*w+1)*16 + lr];
    }

    float fu[8], fv[8];
    unp8(uA0,fu); unp8(vA0,fv);
#pragma unroll
    for (int e=0;e<8;++e){ const float z = fu[e]+fv[e]; s[e]+=z; q[e]=fmaf(z,z,q[e]); }
    unp8(uA1,fu); unp8(vA1,fv);
#pragma unroll
    for (int e=0;e<8;++e){ const float z = fu[e]+fv[e]; s[8+e]+=z; q[8+e]=fmaf(z,z,q[8+e]); }
    unp8(uB0,fu); unp8(vB0,fv);
#pragma unroll
    for (int e=0;e<8;++e){ const float z = fu[e]+fv[e]; s[e]+=z; q[e]=fmaf(z,z,q[e]); }
    unp8(uB1,fu); unp8(vB1,fv);
#pragma unroll
    for (int e=0;e<8;++e){ const float z = fu[e]+fv[e]; s[8+e]+=z; q[8+e]=fmaf(z,z,q[8+e]); }
  }

#pragma unroll
  for (int k=0;k<16;++k){
    float a=s[k]; a+=__shfl_xor(a,1,64); a+=__shfl_xor(a,2,64);
    a+=__shfl_xor(a,4,64); a+=__shfl_xor(a,8,64); s[k]=a;
    float b=q[k]; b+=__shfl_xor(b,1,64); b+=__shfl_xor(b,2,64);
    b+=__shfl_xor(b,4,64); b+=__shfl_xor(b,8,64); q[k]=b;
  }
  if (lr == 0){
#pragma unroll
    for (int e=0;e<8;++e){
      red[w][8*lg+e]    = s[e];
      red[w][32+8*lg+e] = s[8+e];
      red[w][64+8*lg+e] = q[e];
      red[w][96+8*lg+e] = q[8+e];
    }
  }
  __syncthreads();
  if (t < 128)
    part[(size_t)t*NB2 + blockIdx.x] = red[0][t]+red[1][t]+red[2][t]+red[3][t];
}

// ---- kFin: 64 blocks, block c reduces sum/sq rows over nb entries ----------
__global__ __launch_bounds__(256) void kFin(const float* __restrict__ part,
    const float* __restrict__ g, const float* __restrict__ be,
    float* __restrict__ coefs, int nb)
{
  __shared__ float rs[256], rq[256];
  const int c = blockIdx.x, t = threadIdx.x;
  const float* ps = part + (size_t)c*nb;
  const float* pq = part + (size_t)(64+c)*nb;
  float s = 0.f, q = 0.f;
  for (int i=t; i<nb; i+=256){ s += ps[i]; q += pq[i]; }
  rs[t]=s; rq[t]=q;
  __syncthreads();
#pragma unroll
  for (int off=128; off>0; off>>=1){
    if (t < off){ rs[t]+=rs[t+off]; rq[t]+=rq[t+off]; }
    __syncthreads();
  }
  if (t==0){
    const float inv  = 1.0f/(float)NEDGE;
    const float mean = rs[0]*inv;
    const float var  = rq[0]*inv - mean*mean;
    const float a    = g[c]*rsqrtf(var + EPS);
    coefs[c]      = a;
    coefs[64 + c] = be[c] - mean*a;
  }
}

// ---- kScale: U' = a*U + c ; V' = a*V (in place, fold BN1) ------------------
__global__ __launch_bounds__(256) void kScale(unsigned short* __restrict__ Ub,
    unsigned short* __restrict__ Vb, const float* __restrict__ coefs)
{
  const int j = blockIdx.x*256 + threadIdx.x;
  if (j >= N_NODES*8) return;
  const int c0 = (j & 7)*8;
  float a[8], c[8], f[8];
#pragma unroll
  for (int e=0;e<8;++e){ a[e]=coefs[c0+e]; c[e]=coefs[64+c0+e]; }
  bf16x8 u = ((const bf16x8*)Ub)[j];
  unp8(u,f);
#pragma unroll
  for (int e=0;e<8;++e) f[e] = fmaf(a[e], f[e], c[e]);
  ((bf16x8*)Ub)[j] = pack8r(f);
  bf16x8 v = ((const bf16x8*)Vb)[j];
  unp8(v,f);
#pragma unroll
  for (int e=0;e<8;++e) f[e] *= a[e];
  ((bf16x8*)Vb)[j] = pack8r(f);
}

// ---- kS2: 2-node ILP; h1 = lrelu(U'+V'); z2 = h1@W2; stats2 ----------------
__global__ __launch_bounds__(256,4) void kS2(const unsigned short* __restrict__ Ub,
    const unsigned short* __restrict__ Vb, const int* __restrict__ ei,
    const uint4* __restrict__ wfg, float* __restrict__ part)
{
  __shared__ uint4 wlds[512];          // wf2 table, 8 KB
  __shared__ float red[4][128];
  const int t = threadIdx.x, w = t>>6, l = t&63, lr = l&15, lg = l>>4;
  const int G = gridDim.x;
  const f32x4 Z4 = (f32x4){0.f,0.f,0.f,0.f};

  for (int i=t; i<512; i+=256) wlds[i] = wfg[1024+i];
  __syncthreads();

  float sumP[4] = {0,0,0,0}, sqP[4] = {0,0,0,0};

  int tile = blockIdx.x;
  int srcA = ei[tile*128 + (2*w)*16 + lr];
  int srcB = ei[tile*128 + (2*w+1)*16 + lr];
  for (; tile < NTILE2; tile += G){
    const int nA = tile*8 + 2*w, nB = nA + 1;
    bf16x8 uA0,uA1,vA0,vA1, uB0,uB1,vB0,vB1;
    LOADUV(uA0,uA1,vA0,vA1, nA, srcA)
    LOADUV(uB0,uB1,vB0,vB1, nB, srcB)
    const int nt = tile + G;
    if (nt < NTILE2){
      srcA = ei[nt*128 + (2*w)*16 + lr];
      srcB = ei[nt*128 + (2*w+1)*16 + lr];
    }

    H1COMP(hA0, hA1, uA0,uA1,vA0,vA1)
    H1COMP(hB0, hB1, uB0,uB1,vB0,vB1)

    f32x4 aA[4], aB[4];
#pragma unroll
    for (int nf=0;nf<4;++nf){
      const bf16x8 b0 = asfrag(wlds[nf*64 + l]);
      const bf16x8 b1 = asfrag(wlds[(4+nf)*64 + l]);
      aA[nf] = MFMA(hA0, b0, Z4);  aA[nf] = MFMA(hA1, b1, aA[nf]);
      aB[nf] = MFMA(hB0, b0, Z4);  aB[nf] = MFMA(hB1, b1, aB[nf]);
    }
#pragma unroll
    for (int nf=0;nf<4;++nf)
#pragma unroll
      for (int r=0;r<4;++r){
        const float v0 = aA[nf][r], v1 = aB[nf][r];
        sumP[nf] += v0 + v1;
        sqP[nf] = fmaf(v0,v0,sqP[nf]);
        sqP[nf] = fmaf(v1,v1,sqP[nf]);
      }
  }

#pragma unroll
  for (int nf=0;nf<4;++nf){
    float s = sumP[nf], q = sqP[nf];
    s += __shfl_xor(s,16,64); s += __shfl_xor(s,32,64);
    q += __shfl_xor(q,16,64); q += __shfl_xor(q,32,64);
    if (l < 16){ red[w][nf*16+l] = s; red[w][64+nf*16+l] = q; }
  }
  __syncthreads();
  if (t < 128)
    part[(size_t)t*NB2 + blockIdx.x] = red[0][t]+red[1][t]+red[2][t]+red[3][t];
}

// ---- kS3: 2-node ILP; h1 -> z2 -> BN2+lrelu -> z3 -> segmax -> out ---------
__global__ __launch_bounds__(256,4) void kS3(const unsigned short* __restrict__ Ub,
    const unsigned short* __restrict__ Vb, const int* __restrict__ ei,
    const uint4* __restrict__ wfg, const float* __restrict__ coefs2,
    const float* __restrict__ b3, const float* __restrict__ x,
    float* __restrict__ out)
{
  __shared__ uint4 wlds[1024];                              // wf2|wf3, 16 KB
  __shared__ __align__(16) unsigned short buf[8][16][72];   // per-stream, 18 KB
  const int t = threadIdx.x, w = t>>6, l = t&63, lr = l&15, lg = l>>4;
  const int G = gridDim.x;
  const f32x4 Z4 = (f32x4){0.f,0.f,0.f,0.f};

  for (int i=t; i<1024; i+=256) wlds[i] = wfg[1024+i];
  __syncthreads();

  float a2v[4], c2v[4], bb[4];
#pragma unroll
  for (int nf=0;nf<4;++nf){
    a2v[nf]=coefs2[nf*16+lr]; c2v[nf]=coefs2[64+nf*16+lr];
    bb[nf] = b3[nf*16+lr];
  }

  int tile = blockIdx.x;
  int srcA = ei[tile*128 + (2*w)*16 + lr];
  int srcB = ei[tile*128 + (2*w+1)*16 + lr];
  for (; tile < NTILE2; tile += G){
    const int nA = tile*8 + 2*w, nB = nA + 1;
    bf16x8 uA0,uA1,vA0,vA1, uB0,uB1,vB0,vB1;
    LOADUV(uA0,uA1,vA0,vA1, nA, srcA)
    LOADUV(uB0,uB1,vB0,vB1, nB, srcB)
    const int nt = tile + G;
    if (nt < NTILE2){
      srcA = ei[nt*128 + (2*w)*16 + lr];
      srcB = ei[nt*128 + (2*w+1)*16 + lr];
    }

    H1COMP(hA0, hA1, uA0,uA1,vA0,vA1)
    H1COMP(hB0, hB1, uB0,uB1,vB0,vB1)

    // GEMM2 (unswapped): D = z2[edge 4lg+r][ch 16nf+lr]; B shared across streams
    f32x4 aA[4], aB[4];
#pragma unroll
    for (int nf=0;nf<4;++nf){
      const bf16x8 b0 = asfrag(wlds[nf*64 + l]);
      const bf16x8 b1 = asfrag(wlds[(4+nf)*64 + l]);
      aA[nf] = MFMA(hA0, b0, Z4);  aA[nf] = MFMA(hA1, b1, aA[nf]);
      aB[nf] = MFMA(hB0, b0, Z4);  aB[nf] = MFMA(hB1, b1, aB[nf]);
    }
    // BN2 + lrelu -> per-stream transpose buffers
#pragma unroll
    for (int nf=0;nf<4;++nf)
#pragma unroll
      for (int r=0;r<4;++r){
        buf[2*w  ][4*lg+r][16*nf+lr] = f2bfr(lrelu(fmaf(a2v[nf], aA[nf][r], c2v[nf])));
        buf[2*w+1][4*lg+r][16*nf+lr] = f2bfr(lrelu(fmaf(a2v[nf], aB[nf][r], c2v[nf])));
      }
    const bf16x8 gA0 = *(const bf16x8*)&buf[2*w  ][lr][8*lg];
    const bf16x8 gA1 = *(const bf16x8*)&buf[2*w  ][lr][32+8*lg];
    const bf16x8 gB0 = *(const bf16x8*)&buf[2*w+1][lr][8*lg];
    const bf16x8 gB1 = *(const bf16x8*)&buf[2*w+1][lr][32+8*lg];

    f32x4 cA[4], cB[4];
#pragma unroll
    for (int nf=0;nf<4;++nf){
      const bf16x8 b0 = asfrag(wlds[512 + nf*64 + l]);
      const bf16x8 b1 = asfrag(wlds[512 + (4+nf)*64 + l]);
      cA[nf] = MFMA(gA0, b0, Z4);  cA[nf] = MFMA(gA1, b1, cA[nf]);
      cB[nf] = MFMA(gB0, b0, Z4);  cB[nf] = MFMA(gB1, b1, cB[nf]);
    }

    // segmax over each node's 16 edges; bias after max; residual
#pragma unroll
    for (int nf=0;nf<4;++nf){
      float mA = fmaxf(fmaxf(cA[nf][0],cA[nf][1]), fmaxf(cA[nf][2],cA[nf][3]));
      mA = fmaxf(mA, __shfl_xor(mA,16,64));
      mA = fmaxf(mA, __shfl_xor(mA,32,64));
      float mB = fmaxf(fmaxf(cB[nf][0],cB[nf][1]), fmaxf(cB[nf][2],cB[nf][3]));
      mB = fmaxf(mB, __shfl_xor(mB,16,64));
      mB = fmaxf(mB, __shfl_xor(mB,32,64));
      if (l < 16){
        const float xA = x[(size_t)nA*64 + nf*16 + l];
        out[(size_t)nA*64 + nf*16 + l] = lrelu(mA + bb[nf] + xA);
        const float xB = x[(size_t)nB*64 + nf*16 + l];
        out[(size_t)nB*64 + nf*16 + l] = lrelu(mB + bb[nf] + xB);
      }
    }
  }
}

extern "C" void kernel_launch(void* const* d_in, const int* in_sizes, int n_in,
                              void* d_out, int out_size, void* d_ws, size_t ws_size,
                              hipStream_t stream) {
  const float* x   = (const float*)d_in[0];
  const int*   ei  = (const int*)d_in[1];
  const float* W1  = (const float*)d_in[2];
  const float* g1  = (const float*)d_in[4];
  const float* be1 = (const float*)d_in[5];
  const float* W2  = (const float*)d_in[6];
  const float* g2  = (const float*)d_in[8];
  const float* be2 = (const float*)d_in[9];
  const float* W3  = (const float*)d_in[10];
  const float* b3  = (const float*)d_in[11];
  float* out = (float*)d_out;

  // ws: coefs 1KB | part1 512KB | part2 512KB | wfb 32KB | U 6.4MB | V 6.4MB
  float*          coefs = (float*)d_ws;
  float*          part1 = (float*)((char*)d_ws + 1024);
  float*          part2 = part1 + (size_t)NB2*128;
  unsigned short* wfb   = (unsigned short*)((char*)part2 + (size_t)NB2*128*4);
  unsigned short* Ub    = (unsigned short*)((char*)wfb + 32768);
  unsigned short* Vb    = Ub + (size_t)N_NODES*64;

  kInit<<<8, 256, 0, stream>>>(W1, W2, W3, wfb);
  kUV<<<(NWT+3)/4, 256, 0, stream>>>(x, (const uint4*)wfb, Ub, Vb);
  kS1<<<NB2, 256, 0, stream>>>(Ub, Vb, ei, part1);
  kFin<<<64, 256, 0, stream>>>(part1, g1, be1, coefs, NB2);
  kScale<<<(N_NODES*8 + 255)/256, 256, 0, stream>>>(Ub, Vb, coefs);
  kS2<<<NB2, 256, 0, stream>>>(Ub, Vb, ei, (const uint4*)wfb, part2);
  kFin<<<64, 256, 0, stream>>>(part2, g2, be2, coefs + 128, NB2);
  kS3<<<NB2, 256, 0, stream>>>(Ub, Vb, ei, (const uint4*)wfb, coefs + 128,
                               b3, x, out);
}